// Round 5
// baseline (486.951 us; speedup 1.0000x reference)
//
#include <hip/hip_runtime.h>

#define N_NODES 100000
#define DIM     128
#define RR      100
#define NE      400000
#define NBLK    196    // ceil(N_NODES / 512)
#define NPB     32     // dst nodes per gemm block (100000 = 3125 * 32, exact)

typedef float  floatx4 __attribute__((ext_vector_type(4)));
typedef float  floatx2 __attribute__((ext_vector_type(2)));
typedef __bf16 bf16x8  __attribute__((ext_vector_type(8)));

static __device__ __forceinline__ unsigned short f2b(float f) {
    union { float f; unsigned int i; } v; v.f = f;
    unsigned int u = v.i;
    unsigned int r = (u + 0x7fffu + ((u >> 16) & 1u)) >> 16;   // RNE
    return (unsigned short)r;
}
static __device__ __forceinline__ float b2f(unsigned int u16) {
    union { unsigned int i; float f; } v; v.i = u16 << 16; return v.f;
}
static __device__ __forceinline__ unsigned packbf(float a, float b) {
    return (unsigned)f2b(a) | ((unsigned)f2b(b) << 16);
}

// ---- per-dst degree ------------------------------------------------------
__global__ void k_deg(const int* __restrict__ dst, int* __restrict__ deg, int E) {
    int e = blockIdx.x * 256 + threadIdx.x;
    if (e < E) atomicAdd(&deg[dst[e]], 1);
}

// ---- 2-level exclusive scan over deg[N] ----------------------------------
__global__ void k_scan_block(const int* __restrict__ deg, int* __restrict__ bsum) {
    __shared__ int sm[256];
    int b = blockIdx.x, t = threadIdx.x;
    int i0 = b * 512 + 2 * t;
    int a = (i0     < N_NODES) ? deg[i0]     : 0;
    int c = (i0 + 1 < N_NODES) ? deg[i0 + 1] : 0;
    sm[t] = a + c;
    __syncthreads();
    for (int s = 128; s > 0; s >>= 1) { if (t < s) sm[t] += sm[t + s]; __syncthreads(); }
    if (t == 0) bsum[b] = sm[0];
}

__global__ void k_scan_top(const int* __restrict__ bsum, int* __restrict__ boff) {
    __shared__ int sm[256];
    int t = threadIdx.x;
    int v = (t < NBLK) ? bsum[t] : 0;
    sm[t] = v;
    __syncthreads();
    for (int s = 1; s < 256; s <<= 1) {
        int u = (t >= s) ? sm[t - s] : 0;
        __syncthreads();
        sm[t] += u;
        __syncthreads();
    }
    if (t < NBLK) boff[t] = sm[t] - v;   // exclusive
}

__global__ void k_scan_down(const int* __restrict__ deg, const int* __restrict__ boff,
                            int* __restrict__ off) {
    __shared__ int sm[256];
    int b = blockIdx.x, t = threadIdx.x;
    int i0 = b * 512 + 2 * t;
    int a = (i0     < N_NODES) ? deg[i0]     : 0;
    int c = (i0 + 1 < N_NODES) ? deg[i0 + 1] : 0;
    int ts = a + c;
    sm[t] = ts;
    __syncthreads();
    for (int s = 1; s < 256; s <<= 1) {
        int u = (t >= s) ? sm[t - s] : 0;
        __syncthreads();
        sm[t] += u;
        __syncthreads();
    }
    int base = boff[b] + (sm[t] - ts);
    if (i0     < N_NODES) off[i0]     = base;
    if (i0 + 1 < N_NODES) off[i0 + 1] = base + a;
    if (b == 0 && t == 0) off[N_NODES] = NE;
}

// ---- scatter edges into dst-sorted CSR: desc = {src, et<<19|eidx, dst, -}
__global__ void k_scatter(const int* __restrict__ src, const int* __restrict__ dst,
                          const int* __restrict__ et, const int* __restrict__ off,
                          int* __restrict__ cursor, int4* __restrict__ edesc, int E) {
    int e = blockIdx.x * 256 + threadIdx.x;
    if (e >= E) return;
    int d = dst[e];
    int pos = off[d] + atomicAdd(&cursor[d], 1);
    edesc[pos] = make_int4(src[e], (et[e] << 19) | e, d, 0);
}

// ---- schlichtkrull norm + per-edge fp32 weights for BOTH layers ----------
// w_l[p] = (1/count) * comp_l[et]  (float4).  Removes the Cs LDS lookup and
// 4 muls from the per-edge hot loop in k_msg.
__global__ void k_norm2(const int* __restrict__ off, const int4* __restrict__ edesc,
                        const float4* __restrict__ comp1, const float4* __restrict__ comp2,
                        float4* __restrict__ ew1, float4* __restrict__ ew2, int E) {
    int p = blockIdx.x * 256 + threadIdx.x;
    if (p >= E) return;
    int4 me = edesc[p];
    int myt = me.y >> 19;
    int p0 = off[me.z], p1 = off[me.z + 1];
    int c = 0;
    for (int j = p0; j < p1; ++j)
        c += ((((const int*)edesc)[4 * j + 1] >> 19) == myt) ? 1 : 0;
    float nrm = 1.0f / (float)c;
    float4 c1 = comp1[myt], c2 = comp2[myt];
    ew1[p] = make_float4(nrm * c1.x, nrm * c1.y, nrm * c1.z, nrm * c1.w);
    ew2[p] = make_float4(nrm * c2.x, nrm * c2.y, nrm * c2.z, nrm * c2.w);
}

// ---- fused preprocessing: x0 | wt transpose | rel bf16 | penalty | zero --
__global__ void k_pre(const float* __restrict__ ent, const float* __restrict__ entb,
                      const float* __restrict__ bases1, const float* __restrict__ root1,
                      const float* __restrict__ bases2, const float* __restrict__ root2,
                      const float* __restrict__ rel,
                      unsigned short* __restrict__ x1,
                      unsigned short* __restrict__ wt1, unsigned short* __restrict__ wt2,
                      unsigned short* __restrict__ relb, float* __restrict__ out,
                      int* __restrict__ deg, int* __restrict__ cursor) {
    int b = blockIdx.x, t = threadIdx.x;
    if (b < 50000) {                                   // x0 = relu(ent + bias)
        int i = b * 256 + t;
        float v = ent[i] + entb[i & (DIM - 1)];
        x1[i] = f2b(v > 0.0f ? v : 0.0f);
    } else if (b < 50320) {                            // wt[m][k]: bases|root, row-major [128][640]
        int i = (b - 50000) * 256 + t;                 // 128*640
        int m = i / 640, k = i - m * 640;
        float v1, v2;
        if (k < 512) {
            int bb = k >> 7, kin = k & 127;
            v1 = bases1[(bb * 128 + kin) * 128 + m];
            v2 = bases2[(bb * 128 + kin) * 128 + m];
        } else {
            int kin = k - 512;
            v1 = root1[kin * 128 + m];
            v2 = root2[kin * 128 + m];
        }
        wt1[i] = f2b(v1);
        wt2[i] = f2b(v2);
    } else if (b < 50370) {                            // rel -> bf16
        int i = (b - 50320) * 256 + t;                 // 12800
        relb[i] = f2b(rel[i]);
    } else if (b < 51152) {                            // zero deg + cursor
        int j = (b - 50370) * 256 + t;                 // 200192 slots
        if (j < N_NODES) deg[j] = 0;
        else if (j < 2 * N_NODES) cursor[j - N_NODES] = 0;
    } else {                                           // penalty
        __shared__ float sm[256];
        float v = 0.0f;
        for (int i = t; i < RR * DIM; i += 256) { float x = rel[i]; v += x * x; }
        sm[t] = v;
        __syncthreads();
        for (int s = 128; s > 0; s >>= 1) {
            if (t < s) sm[t] += sm[t + s];
            __syncthreads();
        }
        if (t == 0) out[NE] = sm[0];
    }
}

// ---- k_msg: edge aggregation only (split from fused; r4 post-mortem) -----
// 4 independent waves/block, NO LDS, NO barriers -> high occupancy to hide
// the random X gather latency (the ~70us stall in the fused kernel).
// Wave owns 4 rows; per-edge weights are precomputed fp32 (ew).
// Output: bf16 message planes Mg[node][512] (plane-major), coalesced.
#define ACC(A) { A[0] += (floatx2){w0, w0} * xv; \
                 A[1] += (floatx2){w1, w1} * xv; \
                 A[2] += (floatx2){w2, w2} * xv; \
                 A[3] += (floatx2){w3, w3} * xv; }

__global__ __launch_bounds__(256) void k_msg(const unsigned short* __restrict__ X,
                                             const int4* __restrict__ edesc,
                                             const float4* __restrict__ ew,
                                             const int* __restrict__ off,
                                             unsigned short* __restrict__ Mg) {
    const int t = threadIdx.x, lane = t & 63;
    const int nbase = blockIdx.x * 16 + (t >> 6) * 4;
    const int lo = off[nbase], hi = off[nbase + 4];
    floatx2 a0[4], a1[4], a2[4], a3[4];
#pragma unroll
    for (int c = 0; c < 4; ++c) {
        a0[c] = (floatx2)0.0f; a1[c] = (floatx2)0.0f;
        a2[c] = (floatx2)0.0f; a3[c] = (floatx2)0.0f;
    }
    for (int base = lo; base < hi; base += 16) {
        int cnt = hi - base; if (cnt > 16) cnt = 16;
        int4   md = edesc[base + (lane & 15)];
        float4 mw = ew[base + (lane & 15)];
        unsigned xp[16];
#pragma unroll
        for (int u = 0; u < 16; ++u) {                 // 16 independent gathers
            int jc = (u < cnt) ? u : 0;
            int s = (int)__builtin_amdgcn_readlane((unsigned)md.x, (unsigned)jc);
            xp[u] = *(const unsigned*)(X + (size_t)s * 128 + 2 * lane);
        }
#pragma unroll
        for (int u = 0; u < 16; ++u) {
            if (u < cnt) {                             // wave-uniform guard
                int row = (int)__builtin_amdgcn_readlane((unsigned)md.z, (unsigned)u) - nbase;
                float w0 = __int_as_float(__builtin_amdgcn_readlane(__float_as_uint(mw.x), (unsigned)u));
                float w1 = __int_as_float(__builtin_amdgcn_readlane(__float_as_uint(mw.y), (unsigned)u));
                float w2 = __int_as_float(__builtin_amdgcn_readlane(__float_as_uint(mw.z), (unsigned)u));
                float w3 = __int_as_float(__builtin_amdgcn_readlane(__float_as_uint(mw.w), (unsigned)u));
                floatx2 xv = {b2f(xp[u] & 0xffffu), b2f(xp[u] >> 16)};
                if      (row == 0) ACC(a0)
                else if (row == 1) ACC(a1)
                else if (row == 2) ACC(a2)
                else               ACC(a3)
            }
        }
    }
    // write 4 rows x 4 planes, bf16-packed, coalesced 256B per (row,plane)
#pragma unroll
    for (int r = 0; r < 4; ++r) {
        floatx2* A = (r == 0) ? a0 : (r == 1) ? a1 : (r == 2) ? a2 : a3;
#pragma unroll
        for (int c = 0; c < 4; ++c)
            *(unsigned*)(Mg + (size_t)(nbase + r) * 512 + c * 128 + 2 * lane) =
                packbf(A[c].x, A[c].y);
    }
}

// ---- k_gemm: out = [Mg | X] @ WT^T + bias (K=640), r4-proven phase B -----
// m=32 n=128 per block, 8 waves. Bs double-buffered BK=64 (issue-early /
// write-late; r4: hides stage latency, 94.5us fused). A-fragments read
// straight from Mg (L3-resident, no reuse -> no LDS stage). LDS 32KB ->
// occupancy capped by waves (100%), was 2 blocks/CU at 66KB in fused.
__global__ __launch_bounds__(512, 4) void k_gemm(const unsigned short* __restrict__ X,
                                                 const unsigned short* __restrict__ Mg,
                                                 const unsigned short* __restrict__ WT,
                                                 const float* __restrict__ bias,
                                                 unsigned short* __restrict__ out,
                                                 int do_relu) {
    __shared__ __align__(16) unsigned short Bs0[128 * 64];         // 16 KB, ping
    __shared__ __align__(16) unsigned short Bs1[128 * 64];         // 16 KB, pong

    const int t = threadIdx.x, wid = t >> 6, lane = t & 63;
    const int rbase = blockIdx.x * NPB;
    const int quad = lane >> 4, lr = lane & 15;
    const int wr = wid & 1, wc = wid >> 1;             // 2 m-tiles x 4 n-slices

    // staging slots (1024 uint4 per 16KB chunk, 512 thr)
    const int srow0 = t >> 3,        sg0 = t & 7;
    const int srow1 = 64 + (t >> 3), sg1 = t & 7;
    const unsigned bo0 = (unsigned)(srow0 * 64 + ((sg0 ^ (srow0 & 7)) << 3));
    const unsigned bo1 = (unsigned)(srow1 * 64 + ((sg1 ^ (srow1 & 7)) << 3));

    // prologue: chunk-0 loads in flight across ax prefetch
    uint4 p0 = *(const uint4*)(WT + (size_t)srow0 * 640 + sg0 * 8);
    uint4 p1 = *(const uint4*)(WT + (size_t)srow1 * 640 + sg1 * 8);

    // X fragments for chunks 8,9 (root part of K)
    bf16x8 ax[4];
    {
        int grow = rbase + wr * 16 + lr;
#pragma unroll
        for (int ks = 0; ks < 4; ++ks)
            ax[ks] = *(const bf16x8*)(X + (size_t)grow * 128 + ks * 32 + quad * 8);
    }

    floatx4 acc[2];
    acc[0] = (floatx4)0.0f; acc[1] = (floatx4)0.0f;

    *(uint4*)(Bs0 + bo0) = p0;
    *(uint4*)(Bs0 + bo1) = p1;
    __syncthreads();                                   // Bs0 ready

    const int R = wr * 16 + lr;
    const unsigned short* Arow = Mg + (size_t)(rbase + R) * 512;

#pragma unroll
    for (int c = 0; c < 10; ++c) {
        const unsigned short* Bcur = (c & 1) ? Bs1 : Bs0;
        unsigned short*      Bnext = (c & 1) ? Bs0 : Bs1;
        uint4 n0, n1;
        if (c < 9) {                                   // issue next-chunk loads EARLY
            n0 = *(const uint4*)(WT + (size_t)srow0 * 640 + (c + 1) * 64 + sg0 * 8);
            n1 = *(const uint4*)(WT + (size_t)srow1 * 640 + (c + 1) * 64 + sg1 * 8);
        }
#pragma unroll
        for (int ks2 = 0; ks2 < 2; ++ks2) {
            int ks = (c & 1) * 2 + ks2;                // k-subgroup within 128-plane
            bf16x8 a, b0, b1;
            if (c < 8) {
                a = *(const bf16x8*)(Arow + (c >> 1) * 128 + ks * 32 + quad * 8);
            } else {
                a = ax[(c - 8) * 2 + ks2];
            }
            int g = ks2 * 4 + quad;
            int sch = (g ^ (lr & 7)) << 3;
            b0 = *(const bf16x8*)(Bcur + (wc * 32 + lr) * 64 + sch);
            b1 = *(const bf16x8*)(Bcur + (wc * 32 + 16 + lr) * 64 + sch);
            acc[0] = __builtin_amdgcn_mfma_f32_16x16x32_bf16(a, b0, acc[0], 0, 0, 0);
            acc[1] = __builtin_amdgcn_mfma_f32_16x16x32_bf16(a, b1, acc[1], 0, 0, 0);
        }
        if (c < 9) {                                   // write-late: latency hidden
            *(uint4*)(Bnext + bo0) = n0;
            *(uint4*)(Bnext + bo1) = n1;
        }
        __syncthreads();                               // one barrier per round
    }

    // C/D layout: col=lane&15, row=quad*4+reg  [m89/m91-verified]
#pragma unroll
    for (int reg = 0; reg < 4; ++reg) {
        int Ro = wr * 16 + quad * 4 + reg;
        int grow = rbase + Ro;
#pragma unroll
        for (int nj = 0; nj < 2; ++nj) {
            int n = wc * 32 + nj * 16 + lr;
            float v = acc[nj][reg] + bias[n];
            if (do_relu) v = v > 0.0f ? v : 0.0f;
            out[(size_t)grow * 128 + n] = f2b(v);
        }
    }
}

// ---- DistMult score: flat, 16 lanes per edge (r8 measured-fastest) -------
__global__ __launch_bounds__(256) void k_score(const unsigned short* __restrict__ xf,
                                               const int* __restrict__ src, const int* __restrict__ dst,
                                               const int* __restrict__ et,
                                               const unsigned short* __restrict__ relb,
                                               float* __restrict__ out, int E) {
    int g = threadIdx.x >> 4, li = threadIdx.x & 15;
    int e = blockIdx.x * 16 + g;
    if (e >= E) return;
    int s = src[e], d = dst[e], tt = et[e];
    uint4 au = *(const uint4*)(xf + (size_t)s * 128 + li * 8);
    uint4 bu = *(const uint4*)(xf + (size_t)d * 128 + li * 8);
    uint4 ru = *(const uint4*)(relb + (size_t)tt * 128 + li * 8);
    float v;
    v  = b2f(au.x & 0xffffu) * b2f(ru.x & 0xffffu) * b2f(bu.x & 0xffffu);
    v += b2f(au.x >> 16)     * b2f(ru.x >> 16)     * b2f(bu.x >> 16);
    v += b2f(au.y & 0xffffu) * b2f(ru.y & 0xffffu) * b2f(bu.y & 0xffffu);
    v += b2f(au.y >> 16)     * b2f(ru.y >> 16)     * b2f(bu.y >> 16);
    v += b2f(au.z & 0xffffu) * b2f(ru.z & 0xffffu) * b2f(bu.z & 0xffffu);
    v += b2f(au.z >> 16)     * b2f(ru.z >> 16)     * b2f(bu.z >> 16);
    v += b2f(au.w & 0xffffu) * b2f(ru.w & 0xffffu) * b2f(bu.w & 0xffffu);
    v += b2f(au.w >> 16)     * b2f(ru.w >> 16)     * b2f(bu.w >> 16);
    v += __shfl_xor(v, 8, 16);
    v += __shfl_xor(v, 4, 16);
    v += __shfl_xor(v, 2, 16);
    v += __shfl_xor(v, 1, 16);
    if (li == 0) out[e] = v;
}

extern "C" void kernel_launch(void* const* d_in, const int* in_sizes, int n_in,
                              void* d_out, int out_size, void* d_ws, size_t ws_size,
                              hipStream_t stream) {
    (void)in_sizes; (void)n_in; (void)out_size; (void)ws_size;
    const int* edge_index = (const int*)d_in[0];
    const int* edge_type  = (const int*)d_in[1];
    const float* ent    = (const float*)d_in[2];
    const float* entb   = (const float*)d_in[3];
    const float* bases1 = (const float*)d_in[4];
    const float* comp1  = (const float*)d_in[5];
    const float* root1  = (const float*)d_in[6];
    const float* bias1  = (const float*)d_in[7];
    const float* bases2 = (const float*)d_in[8];
    const float* comp2  = (const float*)d_in[9];
    const float* root2  = (const float*)d_in[10];
    const float* bias2  = (const float*)d_in[11];
    const float* rel    = (const float*)d_in[12];
    const int* src = edge_index;
    const int* dst = edge_index + NE;

    char* ws = (char*)d_ws;
    size_t off_b = 0;
    auto alloc = [&](size_t bytes) { void* p = ws + off_b; off_b = (off_b + bytes + 255) & ~(size_t)255; return p; };

    unsigned short* x1   = (unsigned short*)alloc((size_t)N_NODES * 128 * 2);  // 25.6 MB
    unsigned short* x2   = (unsigned short*)alloc((size_t)N_NODES * 128 * 2);  // 25.6 MB
    unsigned short* Mg   = (unsigned short*)alloc((size_t)N_NODES * 512 * 2);  // 102.4 MB
    unsigned short* wt1  = (unsigned short*)alloc(128 * 640 * 2);
    unsigned short* wt2  = (unsigned short*)alloc(128 * 640 * 2);
    unsigned short* relb = (unsigned short*)alloc(RR * DIM * 2);
    int*   deg    = (int*)alloc((size_t)N_NODES * 4);
    int*   cursor = (int*)alloc((size_t)N_NODES * 4);
    int*   offv   = (int*)alloc((size_t)(N_NODES + 1) * 4);
    int*   bsum   = (int*)alloc(NBLK * 4);
    int*   boff   = (int*)alloc(NBLK * 4);
    int4*  edesc  = (int4*)alloc((size_t)(NE + 64) * 16);                      // 6.4 MB + pad
    float4* ew1   = (float4*)alloc((size_t)NE * 16);                           // 6.4 MB
    float4* ew2   = (float4*)alloc((size_t)NE * 16);                           // 6.4 MB

    float* out = (float*)d_out;

    // k_pre first: x0/wt/rel/penalty + zero deg/cursor (replaces 2 memsets)
    k_pre<<<51153, 256, 0, stream>>>(ent, entb, bases1, root1, bases2, root2, rel,
                                     x1, wt1, wt2, relb, out, deg, cursor);
    k_deg<<<(NE + 255) / 256, 256, 0, stream>>>(dst, deg, NE);
    k_scan_block<<<NBLK, 256, 0, stream>>>(deg, bsum);
    k_scan_top<<<1, 256, 0, stream>>>(bsum, boff);
    k_scan_down<<<NBLK, 256, 0, stream>>>(deg, boff, offv);
    k_scatter<<<(NE + 255) / 256, 256, 0, stream>>>(src, dst, edge_type, offv, cursor, edesc, NE);
    k_norm2<<<(NE + 255) / 256, 256, 0, stream>>>(offv, edesc,
                                                  (const float4*)comp1, (const float4*)comp2,
                                                  ew1, ew2, NE);

    int mgrid = N_NODES / 16;    // 6250 (exact)
    int ggrid = N_NODES / NPB;   // 3125 (exact)
    // layer 1: x1 -> x2 (relu)
    k_msg <<<mgrid, 256, 0, stream>>>(x1, edesc, ew1, offv, Mg);
    k_gemm<<<ggrid, 512, 0, stream>>>(x1, Mg, wt1, bias1, x2, 1);
    // layer 2: x2 -> x1 (no relu); x1 becomes xf
    k_msg <<<mgrid, 256, 0, stream>>>(x2, edesc, ew2, offv, Mg);
    k_gemm<<<ggrid, 512, 0, stream>>>(x2, Mg, wt2, bias2, x1, 0);
    // decode
    k_score<<<(NE + 15) / 16, 256, 0, stream>>>(x1, src, dst, edge_type, relb, out, NE);
}

// Round 6
// 400.104 us; speedup vs baseline: 1.2171x; 1.2171x over previous
//
#include <hip/hip_runtime.h>

#define N_NODES 100000
#define DIM     128
#define RR      100
#define NE      400000
#define NBLK    196    // ceil(N_NODES / 512)
#define NPB     32     // dst nodes per fused block (100000 = 3125 * 32, exact)

typedef float  floatx4 __attribute__((ext_vector_type(4)));
typedef float  floatx2 __attribute__((ext_vector_type(2)));
typedef __bf16 bf16x8  __attribute__((ext_vector_type(8)));

static __device__ __forceinline__ unsigned short f2b(float f) {
    union { float f; unsigned int i; } v; v.f = f;
    unsigned int u = v.i;
    unsigned int r = (u + 0x7fffu + ((u >> 16) & 1u)) >> 16;   // RNE
    return (unsigned short)r;
}
static __device__ __forceinline__ float b2f(unsigned int u16) {
    union { unsigned int i; float f; } v; v.i = u16 << 16; return v.f;
}
static __device__ __forceinline__ unsigned packbf(float a, float b) {
    return (unsigned)f2b(a) | ((unsigned)f2b(b) << 16);
}

// ---- per-dst degree ------------------------------------------------------
__global__ void k_deg(const int* __restrict__ dst, int* __restrict__ deg, int E) {
    int e = blockIdx.x * 256 + threadIdx.x;
    if (e < E) atomicAdd(&deg[dst[e]], 1);
}

// ---- 2-level exclusive scan over deg[N] ----------------------------------
__global__ void k_scan_block(const int* __restrict__ deg, int* __restrict__ bsum) {
    __shared__ int sm[256];
    int b = blockIdx.x, t = threadIdx.x;
    int i0 = b * 512 + 2 * t;
    int a = (i0     < N_NODES) ? deg[i0]     : 0;
    int c = (i0 + 1 < N_NODES) ? deg[i0 + 1] : 0;
    sm[t] = a + c;
    __syncthreads();
    for (int s = 128; s > 0; s >>= 1) { if (t < s) sm[t] += sm[t + s]; __syncthreads(); }
    if (t == 0) bsum[b] = sm[0];
}

__global__ void k_scan_top(const int* __restrict__ bsum, int* __restrict__ boff) {
    __shared__ int sm[256];
    int t = threadIdx.x;
    int v = (t < NBLK) ? bsum[t] : 0;
    sm[t] = v;
    __syncthreads();
    for (int s = 1; s < 256; s <<= 1) {
        int u = (t >= s) ? sm[t - s] : 0;
        __syncthreads();
        sm[t] += u;
        __syncthreads();
    }
    if (t < NBLK) boff[t] = sm[t] - v;   // exclusive
}

__global__ void k_scan_down(const int* __restrict__ deg, const int* __restrict__ boff,
                            int* __restrict__ off) {
    __shared__ int sm[256];
    int b = blockIdx.x, t = threadIdx.x;
    int i0 = b * 512 + 2 * t;
    int a = (i0     < N_NODES) ? deg[i0]     : 0;
    int c = (i0 + 1 < N_NODES) ? deg[i0 + 1] : 0;
    int ts = a + c;
    sm[t] = ts;
    __syncthreads();
    for (int s = 1; s < 256; s <<= 1) {
        int u = (t >= s) ? sm[t - s] : 0;
        __syncthreads();
        sm[t] += u;
        __syncthreads();
    }
    int base = boff[b] + (sm[t] - ts);
    if (i0     < N_NODES) off[i0]     = base;
    if (i0 + 1 < N_NODES) off[i0 + 1] = base + a;
    if (b == 0 && t == 0) off[N_NODES] = NE;
}

// ---- scatter edges into dst-sorted CSR: desc = {src, et<<19|eidx, dst, norm}
__global__ void k_scatter(const int* __restrict__ src, const int* __restrict__ dst,
                          const int* __restrict__ et, const int* __restrict__ off,
                          int* __restrict__ cursor, int4* __restrict__ edesc, int E) {
    int e = blockIdx.x * 256 + threadIdx.x;
    if (e >= E) return;
    int d = dst[e];
    int pos = off[d] + atomicAdd(&cursor[d], 1);
    edesc[pos] = make_int4(src[e], (et[e] << 19) | e, d, 0);
}

// ---- schlichtkrull norm: one thread per CSR slot, O(deg) scan ------------
__global__ void k_norm2(const int* __restrict__ off, int4* __restrict__ edesc, int E) {
    int p = blockIdx.x * 256 + threadIdx.x;
    if (p >= E) return;
    int4 me = edesc[p];
    int myt = me.y >> 19;
    int p0 = off[me.z], p1 = off[me.z + 1];
    int c = 0;
    for (int j = p0; j < p1; ++j)
        c += ((((const int*)edesc)[4 * j + 1] >> 19) == myt) ? 1 : 0;
    ((int*)edesc)[4 * p + 3] = __float_as_int(1.0f / (float)c);
}

// ---- fused preprocessing: x0 | wt transpose | rel bf16 | penalty | zero --
__global__ void k_pre(const float* __restrict__ ent, const float* __restrict__ entb,
                      const float* __restrict__ bases1, const float* __restrict__ root1,
                      const float* __restrict__ bases2, const float* __restrict__ root2,
                      const float* __restrict__ rel,
                      unsigned short* __restrict__ x1,
                      unsigned short* __restrict__ wt1, unsigned short* __restrict__ wt2,
                      unsigned short* __restrict__ relb, float* __restrict__ out,
                      int* __restrict__ deg, int* __restrict__ cursor) {
    int b = blockIdx.x, t = threadIdx.x;
    if (b < 50000) {                                   // x0 = relu(ent + bias)
        int i = b * 256 + t;
        float v = ent[i] + entb[i & (DIM - 1)];
        x1[i] = f2b(v > 0.0f ? v : 0.0f);
    } else if (b < 50320) {                            // wt[m][k]: bases|root, row-major [128][640]
        int i = (b - 50000) * 256 + t;                 // 128*640
        int m = i / 640, k = i - m * 640;
        float v1, v2;
        if (k < 512) {
            int bb = k >> 7, kin = k & 127;
            v1 = bases1[(bb * 128 + kin) * 128 + m];
            v2 = bases2[(bb * 128 + kin) * 128 + m];
        } else {
            int kin = k - 512;
            v1 = root1[kin * 128 + m];
            v2 = root2[kin * 128 + m];
        }
        wt1[i] = f2b(v1);
        wt2[i] = f2b(v2);
    } else if (b < 50370) {                            // rel -> bf16
        int i = (b - 50320) * 256 + t;                 // 12800
        relb[i] = f2b(rel[i]);
    } else if (b < 51152) {                            // zero deg + cursor
        int j = (b - 50370) * 256 + t;                 // 200192 slots
        if (j < N_NODES) deg[j] = 0;
        else if (j < 2 * N_NODES) cursor[j - N_NODES] = 0;
    } else {                                           // penalty
        __shared__ float sm[256];
        float v = 0.0f;
        for (int i = t; i < RR * DIM; i += 256) { float x = rel[i]; v += x * x; }
        sm[t] = v;
        __syncthreads();
        for (int s = 128; s > 0; s >>= 1) {
            if (t < s) sm[t] += sm[t + s];
            __syncthreads();
        }
        if (t == 0) out[NE] = sm[0];
    }
}

// ---- fused aggregate + GEMM ----------------------------------------------
// Block = 512 thr (8 waves), 32 dst nodes; wave owns 4 consecutive nodes.
// Phase A: 16-edge batches, 16 prefetched gathers (readlane bases), pk_fma
// fp32 register acc, single bf16 LDS write per (row,chunk).
// Phase B: MFMA K=640, dbuf Bs, BK=32 (r5 post-mortem): Bs 2x8KB -> LDS
// 49.6KB -> 3 blocks/CU (24 waves, was 16 at BK=64/66KB). r5 split proved
// phase A is occupancy-starved (high-occ k_msg 55us vs ~75 fused) and that
// the Mg intermediate costs more than fusion saves (k_gemm 88us). 20 dbuf
// rounds (issue-early/write-late, r4-proven). B swizzle uses (row>>1)&3:
// at 64B row stride, rows alternate 128B-window halves -> 2-way floor.
// LAUNCH BOUNDS: (512,4) — MEASURED. (512,8) caps VGPR at 64 -> scratch
// spill, WRITE_SIZE 25->310 MB, dur 97->190us. Do not cap below 128.
// X fragments (c=16..19) prefetched AFTER phase A (cross-phase preload
// spilled to scratch. Do not hoist.)
#define ACC(A) { A[0] += (floatx2){w0, w0} * xv; \
                 A[1] += (floatx2){w1, w1} * xv; \
                 A[2] += (floatx2){w2, w2} * xv; \
                 A[3] += (floatx2){w3, w3} * xv; }

__global__ __launch_bounds__(512, 4) void k_fused(const unsigned short* __restrict__ X,
                                                  const int4* __restrict__ edesc,
                                                  const int* __restrict__ off,
                                                  const float* __restrict__ comp,
                                                  const unsigned short* __restrict__ WT,
                                                  const float* __restrict__ bias,
                                                  unsigned short* __restrict__ out,
                                                  int do_relu) {
    __shared__ __align__(16) unsigned short Sacc[4 * NPB * 128];   // 32 KB, 4 planes
    __shared__ __align__(16) unsigned short Bs0[128 * 32];         // 8 KB, ping
    __shared__ __align__(16) unsigned short Bs1[128 * 32];         // 8 KB, pong
    __shared__ float4 Cs[RR];                                      // 1.6 KB

    const int t = threadIdx.x, wid = t >> 6, lane = t & 63;
    const int rbase = blockIdx.x * NPB;

    if (t < RR) Cs[t] = ((const float4*)comp)[t];
    __syncthreads();

    // ---------------- phase A: wave owns rows [nbase, nbase+4) ----------------
    {
        const int nbase = rbase + wid * 4;
        const int lo = off[nbase], hi = off[nbase + 4];
        floatx2 a0[4], a1[4], a2[4], a3[4];
#pragma unroll
        for (int c = 0; c < 4; ++c) {
            a0[c] = (floatx2)0.0f; a1[c] = (floatx2)0.0f;
            a2[c] = (floatx2)0.0f; a3[c] = (floatx2)0.0f;
        }
        for (int base = lo; base < hi; base += 16) {
            int cnt = hi - base; if (cnt > 16) cnt = 16;
            int4 md = edesc[base + (lane & 15)];
            unsigned xp[16];
#pragma unroll
            for (int u = 0; u < 16; ++u) {             // 16 independent gathers
                int jc = (u < cnt) ? u : 0;
                int s = (int)__builtin_amdgcn_readlane((unsigned)md.x, (unsigned)jc);
                xp[u] = *(const unsigned*)(X + (size_t)s * 128 + 2 * lane);
            }
#pragma unroll
            for (int u = 0; u < 16; ++u) {
                if (u < cnt) {                         // wave-uniform guard
                    int row = (int)__builtin_amdgcn_readlane((unsigned)md.z, (unsigned)u) - nbase;
                    int tt  = (int)__builtin_amdgcn_readlane((unsigned)md.y, (unsigned)u) >> 19;
                    float w = __int_as_float(__builtin_amdgcn_readlane((unsigned)md.w, (unsigned)u));
                    float4 cc = Cs[tt];
                    floatx2 xv = {b2f(xp[u] & 0xffffu), b2f(xp[u] >> 16)};
                    float w0 = w * cc.x, w1 = w * cc.y, w2 = w * cc.z, w3 = w * cc.w;
                    if      (row == 0) ACC(a0)
                    else if (row == 1) ACC(a1)
                    else if (row == 2) ACC(a2)
                    else               ACC(a3)
                }
            }
        }
        // write 4 rows x 4 chunks, bf16-packed, xor-swizzled 16B chunks
        const int sw16 = lane >> 2, wo = 2 * (lane & 3);
#pragma unroll
        for (int r = 0; r < 4; ++r) {
            int R = wid * 4 + r;
            unsigned bo = (unsigned)(R * 128 + ((sw16 ^ (R & 15)) << 3) + wo);
            floatx2* A = (r == 0) ? a0 : (r == 1) ? a1 : (r == 2) ? a2 : a3;
#pragma unroll
            for (int c = 0; c < 4; ++c)
                *(unsigned*)(Sacc + c * (NPB * 128) + bo) = packbf(A[c].x, A[c].y);
        }
    }

    // ---------------- phase B: MFMA, m=32 n=128 K=640, dbuf Bs (BK=32) --------
    const int quad = lane >> 4, lr = lane & 15;
    const int wr = wid & 1, wc = wid >> 1;             // 2 m-tiles x 4 n-slices

    // staging slot: 512 uint4 per 8KB chunk, 512 thr -> 1 each
    const int srow = t >> 2, sg = t & 3;
    const unsigned bo = (unsigned)(srow * 32 + ((sg ^ ((srow >> 1) & 3)) << 3));

    // prologue: chunk-0 load in flight across ax prefetch
    uint4 p0 = *(const uint4*)(WT + (size_t)srow * 640 + sg * 8);

    // prefetch X fragments for rounds 16..19 (root part of K)
    bf16x8 ax[4];
    {
        int grow = rbase + wr * 16 + lr;               // always < N (3125*32 exact)
#pragma unroll
        for (int ks = 0; ks < 4; ++ks)
            ax[ks] = *(const bf16x8*)(X + (size_t)grow * 128 + ks * 32 + quad * 8);
    }

    floatx4 acc[2];
    acc[0] = (floatx4)0.0f; acc[1] = (floatx4)0.0f;

    *(uint4*)(Bs0 + bo) = p0;                          // compiler inserts vmcnt wait
    __syncthreads();                                   // Sacc + Bs0 ready

    const int R = wr * 16 + lr;
    const int brow0 = wc * 32 + lr, brow1 = brow0 + 16;
    const unsigned bq0 = (unsigned)(brow0 * 32 + ((quad ^ ((brow0 >> 1) & 3)) << 3));
    const unsigned bq1 = (unsigned)(brow1 * 32 + ((quad ^ ((brow1 >> 1) & 3)) << 3));

#pragma unroll
    for (int c = 0; c < 20; ++c) {
        const unsigned short* Bcur = (c & 1) ? Bs1 : Bs0;
        unsigned short*      Bnext = (c & 1) ? Bs0 : Bs1;
        uint4 nx;
        if (c < 19)                                    // issue next-chunk load EARLY
            nx = *(const uint4*)(WT + (size_t)srow * 640 + (c + 1) * 32 + sg * 8);
        bf16x8 a, b0, b1;
        if (c < 16) {
            int ch = (((c & 3) * 4 + quad) ^ (R & 15)) << 3;
            a = *(const bf16x8*)(Sacc + (c >> 2) * (NPB * 128) + R * 128 + ch);
        } else {
            a = ax[c - 16];
        }
        b0 = *(const bf16x8*)(Bcur + bq0);
        b1 = *(const bf16x8*)(Bcur + bq1);
        acc[0] = __builtin_amdgcn_mfma_f32_16x16x32_bf16(a, b0, acc[0], 0, 0, 0);
        acc[1] = __builtin_amdgcn_mfma_f32_16x16x32_bf16(a, b1, acc[1], 0, 0, 0);
        if (c < 19)                                    // write-late: latency hidden
            *(uint4*)(Bnext + bo) = nx;
        __syncthreads();                               // one barrier per round
    }

    // C/D layout: col=lane&15, row=quad*4+reg  [m89/m91-verified]
#pragma unroll
    for (int reg = 0; reg < 4; ++reg) {
        int Ro = wr * 16 + quad * 4 + reg;
        int grow = rbase + Ro;
#pragma unroll
        for (int nj = 0; nj < 2; ++nj) {
            int n = wc * 32 + nj * 16 + lr;
            float v = acc[nj][reg] + bias[n];
            if (do_relu) v = v > 0.0f ? v : 0.0f;
            out[(size_t)grow * 128 + n] = f2b(v);
        }
    }
}

// ---- DistMult score: flat, 16 lanes per edge (r8 measured-fastest) -------
__global__ __launch_bounds__(256) void k_score(const unsigned short* __restrict__ xf,
                                               const int* __restrict__ src, const int* __restrict__ dst,
                                               const int* __restrict__ et,
                                               const unsigned short* __restrict__ relb,
                                               float* __restrict__ out, int E) {
    int g = threadIdx.x >> 4, li = threadIdx.x & 15;
    int e = blockIdx.x * 16 + g;
    if (e >= E) return;
    int s = src[e], d = dst[e], tt = et[e];
    uint4 au = *(const uint4*)(xf + (size_t)s * 128 + li * 8);
    uint4 bu = *(const uint4*)(xf + (size_t)d * 128 + li * 8);
    uint4 ru = *(const uint4*)(relb + (size_t)tt * 128 + li * 8);
    float v;
    v  = b2f(au.x & 0xffffu) * b2f(ru.x & 0xffffu) * b2f(bu.x & 0xffffu);
    v += b2f(au.x >> 16)     * b2f(ru.x >> 16)     * b2f(bu.x >> 16);
    v += b2f(au.y & 0xffffu) * b2f(ru.y & 0xffffu) * b2f(bu.y & 0xffffu);
    v += b2f(au.y >> 16)     * b2f(ru.y >> 16)     * b2f(bu.y >> 16);
    v += b2f(au.z & 0xffffu) * b2f(ru.z & 0xffffu) * b2f(bu.z & 0xffffu);
    v += b2f(au.z >> 16)     * b2f(ru.z >> 16)     * b2f(bu.z >> 16);
    v += b2f(au.w & 0xffffu) * b2f(ru.w & 0xffffu) * b2f(bu.w & 0xffffu);
    v += b2f(au.w >> 16)     * b2f(ru.w >> 16)     * b2f(bu.w >> 16);
    v += __shfl_xor(v, 8, 16);
    v += __shfl_xor(v, 4, 16);
    v += __shfl_xor(v, 2, 16);
    v += __shfl_xor(v, 1, 16);
    if (li == 0) out[e] = v;
}

extern "C" void kernel_launch(void* const* d_in, const int* in_sizes, int n_in,
                              void* d_out, int out_size, void* d_ws, size_t ws_size,
                              hipStream_t stream) {
    (void)in_sizes; (void)n_in; (void)out_size; (void)ws_size;
    const int* edge_index = (const int*)d_in[0];
    const int* edge_type  = (const int*)d_in[1];
    const float* ent    = (const float*)d_in[2];
    const float* entb   = (const float*)d_in[3];
    const float* bases1 = (const float*)d_in[4];
    const float* comp1  = (const float*)d_in[5];
    const float* root1  = (const float*)d_in[6];
    const float* bias1  = (const float*)d_in[7];
    const float* bases2 = (const float*)d_in[8];
    const float* comp2  = (const float*)d_in[9];
    const float* root2  = (const float*)d_in[10];
    const float* bias2  = (const float*)d_in[11];
    const float* rel    = (const float*)d_in[12];
    const int* src = edge_index;
    const int* dst = edge_index + NE;

    char* ws = (char*)d_ws;
    size_t off_b = 0;
    auto alloc = [&](size_t bytes) { void* p = ws + off_b; off_b = (off_b + bytes + 255) & ~(size_t)255; return p; };

    unsigned short* x1   = (unsigned short*)alloc((size_t)N_NODES * 128 * 2);  // 25.6 MB
    unsigned short* x2   = (unsigned short*)alloc((size_t)N_NODES * 128 * 2);  // 25.6 MB
    unsigned short* wt1  = (unsigned short*)alloc(128 * 640 * 2);
    unsigned short* wt2  = (unsigned short*)alloc(128 * 640 * 2);
    unsigned short* relb = (unsigned short*)alloc(RR * DIM * 2);
    int*   deg    = (int*)alloc((size_t)N_NODES * 4);
    int*   cursor = (int*)alloc((size_t)N_NODES * 4);
    int*   offv   = (int*)alloc((size_t)(N_NODES + 1) * 4);
    int*   bsum   = (int*)alloc(NBLK * 4);
    int*   boff   = (int*)alloc(NBLK * 4);
    int4*  edesc  = (int4*)alloc((size_t)(NE + 64) * 16);                      // 6.4 MB + pad

    float* out = (float*)d_out;

    // k_pre first: x0/wt/rel/penalty + zero deg/cursor (replaces 2 memsets)
    k_pre<<<51153, 256, 0, stream>>>(ent, entb, bases1, root1, bases2, root2, rel,
                                     x1, wt1, wt2, relb, out, deg, cursor);
    k_deg<<<(NE + 255) / 256, 256, 0, stream>>>(dst, deg, NE);
    k_scan_block<<<NBLK, 256, 0, stream>>>(deg, bsum);
    k_scan_top<<<1, 256, 0, stream>>>(bsum, boff);
    k_scan_down<<<NBLK, 256, 0, stream>>>(deg, boff, offv);
    k_scatter<<<(NE + 255) / 256, 256, 0, stream>>>(src, dst, edge_type, offv, cursor, edesc, NE);
    k_norm2<<<(NE + 255) / 256, 256, 0, stream>>>(offv, edesc, NE);

    int fgrid = N_NODES / NPB;   // 3125 (exact)
    // layer 1: x1 -> x2 (relu)
    k_fused<<<fgrid, 512, 0, stream>>>(x1, edesc, offv, comp1, wt1, bias1, x2, 1);
    // layer 2: x2 -> x1 (no relu); x1 becomes xf
    k_fused<<<fgrid, 512, 0, stream>>>(x2, edesc, offv, comp2, wt2, bias2, x1, 0);
    // decode
    k_score<<<(NE + 15) / 16, 256, 0, stream>>>(x1, src, dst, edge_type, relb, out, NE);
}

// Round 8
// 377.937 us; speedup vs baseline: 1.2884x; 1.0587x over previous
//
#include <hip/hip_runtime.h>

#define N_NODES 100000
#define DIM     128
#define RR      100
#define NE      400000
#define NBLK    196    // ceil(N_NODES / 512)
#define NPB     32     // dst nodes per fused block (100000 = 3125 * 32, exact)

typedef float  floatx4 __attribute__((ext_vector_type(4)));
typedef float  floatx2 __attribute__((ext_vector_type(2)));
typedef __bf16 bf16x8  __attribute__((ext_vector_type(8)));

static __device__ __forceinline__ unsigned short f2b(float f) {
    union { float f; unsigned int i; } v; v.f = f;
    unsigned int u = v.i;
    unsigned int r = (u + 0x7fffu + ((u >> 16) & 1u)) >> 16;   // RNE
    return (unsigned short)r;
}
static __device__ __forceinline__ float b2f(unsigned int u16) {
    union { unsigned int i; float f; } v; v.i = u16 << 16; return v.f;
}
static __device__ __forceinline__ unsigned packbf(float a, float b) {
    return (unsigned)f2b(a) | ((unsigned)f2b(b) << 16);
}

// ---- per-dst degree ------------------------------------------------------
__global__ void k_deg(const int* __restrict__ dst, int* __restrict__ deg, int E) {
    int e = blockIdx.x * 256 + threadIdx.x;
    if (e < E) atomicAdd(&deg[dst[e]], 1);
}

// ---- 2-level exclusive scan over deg[N] ----------------------------------
__global__ void k_scan_block(const int* __restrict__ deg, int* __restrict__ bsum) {
    __shared__ int sm[256];
    int b = blockIdx.x, t = threadIdx.x;
    int i0 = b * 512 + 2 * t;
    int a = (i0     < N_NODES) ? deg[i0]     : 0;
    int c = (i0 + 1 < N_NODES) ? deg[i0 + 1] : 0;
    sm[t] = a + c;
    __syncthreads();
    for (int s = 128; s > 0; s >>= 1) { if (t < s) sm[t] += sm[t + s]; __syncthreads(); }
    if (t == 0) bsum[b] = sm[0];
}

__global__ void k_scan_top(const int* __restrict__ bsum, int* __restrict__ boff) {
    __shared__ int sm[256];
    int t = threadIdx.x;
    int v = (t < NBLK) ? bsum[t] : 0;
    sm[t] = v;
    __syncthreads();
    for (int s = 1; s < 256; s <<= 1) {
        int u = (t >= s) ? sm[t - s] : 0;
        __syncthreads();
        sm[t] += u;
        __syncthreads();
    }
    if (t < NBLK) boff[t] = sm[t] - v;   // exclusive
}

__global__ void k_scan_down(const int* __restrict__ deg, const int* __restrict__ boff,
                            int* __restrict__ off) {
    __shared__ int sm[256];
    int b = blockIdx.x, t = threadIdx.x;
    int i0 = b * 512 + 2 * t;
    int a = (i0     < N_NODES) ? deg[i0]     : 0;
    int c = (i0 + 1 < N_NODES) ? deg[i0 + 1] : 0;
    int ts = a + c;
    sm[t] = ts;
    __syncthreads();
    for (int s = 1; s < 256; s <<= 1) {
        int u = (t >= s) ? sm[t - s] : 0;
        __syncthreads();
        sm[t] += u;
        __syncthreads();
    }
    int base = boff[b] + (sm[t] - ts);
    if (i0     < N_NODES) off[i0]     = base;
    if (i0 + 1 < N_NODES) off[i0 + 1] = base + a;
    if (b == 0 && t == 0) off[N_NODES] = NE;
}

// ---- scatter edges into dst-sorted CSR: desc = {src, et<<19|eidx, dst, norm}
__global__ void k_scatter(const int* __restrict__ src, const int* __restrict__ dst,
                          const int* __restrict__ et, const int* __restrict__ off,
                          int* __restrict__ cursor, int4* __restrict__ edesc, int E) {
    int e = blockIdx.x * 256 + threadIdx.x;
    if (e >= E) return;
    int d = dst[e];
    int pos = off[d] + atomicAdd(&cursor[d], 1);
    edesc[pos] = make_int4(src[e], (et[e] << 19) | e, d, 0);
}

// ---- schlichtkrull norm: one thread per CSR slot, O(deg) scan ------------
__global__ void k_norm2(const int* __restrict__ off, int4* __restrict__ edesc, int E) {
    int p = blockIdx.x * 256 + threadIdx.x;
    if (p >= E) return;
    int4 me = edesc[p];
    int myt = me.y >> 19;
    int p0 = off[me.z], p1 = off[me.z + 1];
    int c = 0;
    for (int j = p0; j < p1; ++j)
        c += ((((const int*)edesc)[4 * j + 1] >> 19) == myt) ? 1 : 0;
    ((int*)edesc)[4 * p + 3] = __float_as_int(1.0f / (float)c);
}

// ---- fused preprocessing: x0(vec8) | wt transpose | rel bf16 | zero | pen
// BLOCK RANGES (r7 crash lesson: rel branch MUST be exactly 12800/256 = 50
// blocks; 70 blocks wrote OOB past relb into deg -> corrupted CSR -> fault):
//   [0,6250)      x0: 12.8M elems, 8/thr
//   [6250,6570)   wt: 320 blocks = 81920 = 128*640
//   [6570,6620)   rel: 50 blocks = 12800
//   [6620,7402)   zero: 782 blocks = 200192 >= 200000
//   7402          penalty
__global__ void k_pre(const float* __restrict__ ent, const float* __restrict__ entb,
                      const float* __restrict__ bases1, const float* __restrict__ root1,
                      const float* __restrict__ bases2, const float* __restrict__ root2,
                      const float* __restrict__ rel,
                      unsigned short* __restrict__ x1,
                      unsigned short* __restrict__ wt1, unsigned short* __restrict__ wt2,
                      unsigned short* __restrict__ relb, float* __restrict__ out,
                      int* __restrict__ deg, int* __restrict__ cursor) {
    int b = blockIdx.x, t = threadIdx.x;
    if (b < 6250) {                                    // x0 = relu(ent + bias), 8/thr
        int i = (b * 256 + t) * 8;                     // 12.8M elems
        float4 v0 = *(const float4*)(ent + i);
        float4 v1 = *(const float4*)(ent + i + 4);
        int k = i & (DIM - 1);                         // 8-aligned col
        float4 e0 = *(const float4*)(entb + k);
        float4 e1 = *(const float4*)(entb + k + 4);
        unsigned r0 = packbf(fmaxf(v0.x + e0.x, 0.0f), fmaxf(v0.y + e0.y, 0.0f));
        unsigned r1 = packbf(fmaxf(v0.z + e0.z, 0.0f), fmaxf(v0.w + e0.w, 0.0f));
        unsigned r2 = packbf(fmaxf(v1.x + e1.x, 0.0f), fmaxf(v1.y + e1.y, 0.0f));
        unsigned r3 = packbf(fmaxf(v1.z + e1.z, 0.0f), fmaxf(v1.w + e1.w, 0.0f));
        *(uint4*)(x1 + i) = make_uint4(r0, r1, r2, r3);
    } else if (b < 6570) {                             // wt[m][k]: bases|root, row-major [128][640]
        int i = (b - 6250) * 256 + t;                  // 128*640
        int m = i / 640, k = i - m * 640;
        float v1, v2;
        if (k < 512) {
            int bb = k >> 7, kin = k & 127;
            v1 = bases1[(bb * 128 + kin) * 128 + m];
            v2 = bases2[(bb * 128 + kin) * 128 + m];
        } else {
            int kin = k - 512;
            v1 = root1[kin * 128 + m];
            v2 = root2[kin * 128 + m];
        }
        wt1[i] = f2b(v1);
        wt2[i] = f2b(v2);
    } else if (b < 6620) {                             // rel -> bf16 (EXACTLY 50 blocks)
        int i = (b - 6570) * 256 + t;                  // 12800
        relb[i] = f2b(rel[i]);
    } else if (b < 7402) {                             // zero deg + cursor
        int j = (b - 6620) * 256 + t;                  // 200192 slots
        if (j < N_NODES) deg[j] = 0;
        else if (j < 2 * N_NODES) cursor[j - N_NODES] = 0;
    } else {                                           // penalty
        __shared__ float sm[256];
        float v = 0.0f;
        for (int i = t; i < RR * DIM; i += 256) { float x = rel[i]; v += x * x; }
        sm[t] = v;
        __syncthreads();
        for (int s = 128; s > 0; s >>= 1) {
            if (t < s) sm[t] += sm[t + s];
            __syncthreads();
        }
        if (t == 0) out[NE] = sm[0];
    }
}

// ---- fused aggregate + GEMM (r4 champion form, 94.5us measured) ----------
// Block = 512 thr (8 waves), 32 dst nodes; wave owns 4 consecutive nodes.
// Phase A: 16-edge batches, 16 prefetched gathers (readlane bases), pk_fma
// fp32 register acc, single bf16 LDS write per (row,chunk).
// Phase B: MFMA K=640, DOUBLE-BUFFERED Bs (BK=64 x2 = 32KB): issue loads
// for round c+1 -> MFMA on Bs[c&1] -> ds_write Bs[~c] -> barrier.
// MEASURED LADDER: r0 sync BK=128: 97.4 | r2 unstaged: 119 | r3 sync BK=64:
// 112.6 | r4 dbuf BK=64: 94.5 (best) | r6 dbuf BK=32: 100.6.
// Occupancy metric invariant (~39%) across LDS 35/51/66KB — not a lever.
// LAUNCH BOUNDS: (512,4) — MEASURED. (512,8) caps VGPR at 64 -> scratch
// spill, WRITE_SIZE 25->310 MB, dur 97->190us. Do not cap below 128.
// X fragments (c=8,9) prefetched AFTER phase A (cross-phase preload
// spilled to scratch. Do not hoist.)
#define ACC(A) { A[0] += (floatx2){w0, w0} * xv; \
                 A[1] += (floatx2){w1, w1} * xv; \
                 A[2] += (floatx2){w2, w2} * xv; \
                 A[3] += (floatx2){w3, w3} * xv; }

__global__ __launch_bounds__(512, 4) void k_fused(const unsigned short* __restrict__ X,
                                                  const int4* __restrict__ edesc,
                                                  const int* __restrict__ off,
                                                  const float* __restrict__ comp,
                                                  const unsigned short* __restrict__ WT,
                                                  const float* __restrict__ bias,
                                                  unsigned short* __restrict__ out,
                                                  int do_relu) {
    __shared__ __align__(16) unsigned short Sacc[4 * NPB * 128];   // 32 KB, 4 planes
    __shared__ __align__(16) unsigned short Bs0[128 * 64];         // 16 KB, ping
    __shared__ __align__(16) unsigned short Bs1[128 * 64];         // 16 KB, pong
    __shared__ float4 Cs[RR];                                      // 1.6 KB

    const int t = threadIdx.x, wid = t >> 6, lane = t & 63;
    const int rbase = blockIdx.x * NPB;

    if (t < RR) Cs[t] = ((const float4*)comp)[t];
    __syncthreads();

    // ---------------- phase A: wave owns rows [nbase, nbase+4) ----------------
    {
        const int nbase = rbase + wid * 4;
        const int lo = off[nbase], hi = off[nbase + 4];
        floatx2 a0[4], a1[4], a2[4], a3[4];
#pragma unroll
        for (int c = 0; c < 4; ++c) {
            a0[c] = (floatx2)0.0f; a1[c] = (floatx2)0.0f;
            a2[c] = (floatx2)0.0f; a3[c] = (floatx2)0.0f;
        }
        for (int base = lo; base < hi; base += 16) {
            int cnt = hi - base; if (cnt > 16) cnt = 16;
            int4 md = edesc[base + (lane & 15)];
            unsigned xp[16];
#pragma unroll
            for (int u = 0; u < 16; ++u) {             // 16 independent gathers
                int jc = (u < cnt) ? u : 0;
                int s = (int)__builtin_amdgcn_readlane((unsigned)md.x, (unsigned)jc);
                xp[u] = *(const unsigned*)(X + (size_t)s * 128 + 2 * lane);
            }
#pragma unroll
            for (int u = 0; u < 16; ++u) {
                if (u < cnt) {                         // wave-uniform guard
                    int row = (int)__builtin_amdgcn_readlane((unsigned)md.z, (unsigned)u) - nbase;
                    int tt  = (int)__builtin_amdgcn_readlane((unsigned)md.y, (unsigned)u) >> 19;
                    float w = __int_as_float(__builtin_amdgcn_readlane((unsigned)md.w, (unsigned)u));
                    float4 cc = Cs[tt];
                    floatx2 xv = {b2f(xp[u] & 0xffffu), b2f(xp[u] >> 16)};
                    float w0 = w * cc.x, w1 = w * cc.y, w2 = w * cc.z, w3 = w * cc.w;
                    if      (row == 0) ACC(a0)
                    else if (row == 1) ACC(a1)
                    else if (row == 2) ACC(a2)
                    else               ACC(a3)
                }
            }
        }
        // write 4 rows x 4 chunks, bf16-packed, xor-swizzled 16B chunks
        const int sw16 = lane >> 2, wo = 2 * (lane & 3);
#pragma unroll
        for (int r = 0; r < 4; ++r) {
            int R = wid * 4 + r;
            unsigned bo = (unsigned)(R * 128 + ((sw16 ^ (R & 15)) << 3) + wo);
            floatx2* A = (r == 0) ? a0 : (r == 1) ? a1 : (r == 2) ? a2 : a3;
#pragma unroll
            for (int c = 0; c < 4; ++c)
                *(unsigned*)(Sacc + c * (NPB * 128) + bo) = packbf(A[c].x, A[c].y);
        }
    }

    // ---------------- phase B: MFMA, m=32 n=128 K=640, dbuf Bs (BK=64) --------
    const int quad = lane >> 4, lr = lane & 15;
    const int wr = wid & 1, wc = wid >> 1;             // 2 m-tiles x 4 n-slices

    // this thread's two staging slots (1024 uint4 per 16KB chunk, 512 thr)
    const int srow0 = t >> 3,        sg0 = t & 7;          // idx = t
    const int srow1 = 64 + (t >> 3), sg1 = t & 7;          // idx = 512 + t
    const unsigned bo0 = (unsigned)(srow0 * 64 + ((sg0 ^ (srow0 & 7)) << 3));
    const unsigned bo1 = (unsigned)(srow1 * 64 + ((sg1 ^ (srow1 & 7)) << 3));

    // prologue: issue chunk-0 loads first (in flight across ax + barrier)
    uint4 p0 = *(const uint4*)(WT + (size_t)srow0 * 640 + sg0 * 8);
    uint4 p1 = *(const uint4*)(WT + (size_t)srow1 * 640 + sg1 * 8);

    // prefetch X fragments for chunks 8,9 (hidden behind chunk 0..7 compute)
    bf16x8 ax[4];
    {
        int grow = rbase + wr * 16 + lr;               // always < N (3125*32 exact)
#pragma unroll
        for (int ks = 0; ks < 4; ++ks)
            ax[ks] = *(const bf16x8*)(X + (size_t)grow * 128 + ks * 32 + quad * 8);
    }

    floatx4 acc[2];
    acc[0] = (floatx4)0.0f; acc[1] = (floatx4)0.0f;

    *(uint4*)(Bs0 + bo0) = p0;                         // compiler inserts vmcnt wait
    *(uint4*)(Bs0 + bo1) = p1;
    __syncthreads();                                   // Sacc + Bs0 ready

#pragma unroll
    for (int c = 0; c < 10; ++c) {
        const unsigned short* Bcur = (c & 1) ? Bs1 : Bs0;
        unsigned short*      Bnext = (c & 1) ? Bs0 : Bs1;
        uint4 n0, n1;
        if (c < 9) {                                   // issue next-chunk loads EARLY
            n0 = *(const uint4*)(WT + (size_t)srow0 * 640 + (c + 1) * 64 + sg0 * 8);
            n1 = *(const uint4*)(WT + (size_t)srow1 * 640 + (c + 1) * 64 + sg1 * 8);
        }
#pragma unroll
        for (int ks2 = 0; ks2 < 2; ++ks2) {
            int ks = (c & 1) * 2 + ks2;                // k-subgroup within 128-plane
            bf16x8 a, b0, b1;
            int R = wr * 16 + lr;
            if (c < 8) {
                int ch = ((ks * 4 + quad) ^ (R & 15)) << 3;
                a = *(const bf16x8*)(Sacc + (c >> 1) * (NPB * 128) + R * 128 + ch);
            } else {
                a = ax[(c - 8) * 2 + ks2];
            }
            int g = ks2 * 4 + quad;
            int sch = (g ^ (lr & 7)) << 3;
            b0 = *(const bf16x8*)(Bcur + (wc * 32 + lr) * 64 + sch);
            b1 = *(const bf16x8*)(Bcur + (wc * 32 + 16 + lr) * 64 + sch);
            acc[0] = __builtin_amdgcn_mfma_f32_16x16x32_bf16(a, b0, acc[0], 0, 0, 0);
            acc[1] = __builtin_amdgcn_mfma_f32_16x16x32_bf16(a, b1, acc[1], 0, 0, 0);
        }
        if (c < 9) {                                   // write-late: latency hidden
            *(uint4*)(Bnext + bo0) = n0;
            *(uint4*)(Bnext + bo1) = n1;
        }
        __syncthreads();                               // one barrier per round
    }

    // C/D layout: col=lane&15, row=quad*4+reg  [m89/m91-verified]
#pragma unroll
    for (int reg = 0; reg < 4; ++reg) {
        int R = wr * 16 + quad * 4 + reg;
        int grow = rbase + R;
#pragma unroll
        for (int nj = 0; nj < 2; ++nj) {
            int n = wc * 32 + nj * 16 + lr;
            float v = acc[nj][reg] + bias[n];
            if (do_relu) v = v > 0.0f ? v : 0.0f;
            out[(size_t)grow * 128 + n] = f2b(v);
        }
    }
}

// ---- DistMult score: 16 lanes x 4 edges per group (12 outstanding loads) -
static __device__ __forceinline__ float dot8(uint4 a, uint4 r, uint4 b) {
    float v;
    v  = b2f(a.x & 0xffffu) * b2f(r.x & 0xffffu) * b2f(b.x & 0xffffu);
    v += b2f(a.x >> 16)     * b2f(r.x >> 16)     * b2f(b.x >> 16);
    v += b2f(a.y & 0xffffu) * b2f(r.y & 0xffffu) * b2f(b.y & 0xffffu);
    v += b2f(a.y >> 16)     * b2f(r.y >> 16)     * b2f(b.y >> 16);
    v += b2f(a.z & 0xffffu) * b2f(r.z & 0xffffu) * b2f(b.z & 0xffffu);
    v += b2f(a.z >> 16)     * b2f(r.z >> 16)     * b2f(b.z >> 16);
    v += b2f(a.w & 0xffffu) * b2f(r.w & 0xffffu) * b2f(b.w & 0xffffu);
    v += b2f(a.w >> 16)     * b2f(r.w >> 16)     * b2f(b.w >> 16);
    return v;
}

__global__ __launch_bounds__(256) void k_score(const unsigned short* __restrict__ xf,
                                               const int* __restrict__ src, const int* __restrict__ dst,
                                               const int* __restrict__ et,
                                               const unsigned short* __restrict__ relb,
                                               float* __restrict__ out, int E) {
    int g = threadIdx.x >> 4, li = threadIdx.x & 15;
    int e0 = blockIdx.x * 64 + g * 4;                  // grid 6250: 6250*64 = 400000 exact
    int s0 = src[e0],     d0 = dst[e0],     t0 = et[e0];
    int s1 = src[e0 + 1], d1 = dst[e0 + 1], t1 = et[e0 + 1];
    int s2 = src[e0 + 2], d2 = dst[e0 + 2], t2 = et[e0 + 2];
    int s3 = src[e0 + 3], d3 = dst[e0 + 3], t3 = et[e0 + 3];
    size_t lo = (size_t)li * 8;
    uint4 a0 = *(const uint4*)(xf + (size_t)s0 * 128 + lo);
    uint4 b0 = *(const uint4*)(xf + (size_t)d0 * 128 + lo);
    uint4 a1 = *(const uint4*)(xf + (size_t)s1 * 128 + lo);
    uint4 b1 = *(const uint4*)(xf + (size_t)d1 * 128 + lo);
    uint4 a2 = *(const uint4*)(xf + (size_t)s2 * 128 + lo);
    uint4 b2 = *(const uint4*)(xf + (size_t)d2 * 128 + lo);
    uint4 a3 = *(const uint4*)(xf + (size_t)s3 * 128 + lo);
    uint4 b3 = *(const uint4*)(xf + (size_t)d3 * 128 + lo);
    uint4 r0 = *(const uint4*)(relb + (size_t)t0 * 128 + lo);
    uint4 r1 = *(const uint4*)(relb + (size_t)t1 * 128 + lo);
    uint4 r2 = *(const uint4*)(relb + (size_t)t2 * 128 + lo);
    uint4 r3 = *(const uint4*)(relb + (size_t)t3 * 128 + lo);
    float v0 = dot8(a0, r0, b0);
    float v1 = dot8(a1, r1, b1);
    float v2 = dot8(a2, r2, b2);
    float v3 = dot8(a3, r3, b3);
#pragma unroll
    for (int s = 8; s > 0; s >>= 1) {
        v0 += __shfl_xor(v0, s, 16);
        v1 += __shfl_xor(v1, s, 16);
        v2 += __shfl_xor(v2, s, 16);
        v3 += __shfl_xor(v3, s, 16);
    }
    if (li == 0) {
        out[e0]     = v0;
        out[e0 + 1] = v1;
        out[e0 + 2] = v2;
        out[e0 + 3] = v3;
    }
}

extern "C" void kernel_launch(void* const* d_in, const int* in_sizes, int n_in,
                              void* d_out, int out_size, void* d_ws, size_t ws_size,
                              hipStream_t stream) {
    (void)in_sizes; (void)n_in; (void)out_size; (void)ws_size;
    const int* edge_index = (const int*)d_in[0];
    const int* edge_type  = (const int*)d_in[1];
    const float* ent    = (const float*)d_in[2];
    const float* entb   = (const float*)d_in[3];
    const float* bases1 = (const float*)d_in[4];
    const float* comp1  = (const float*)d_in[5];
    const float* root1  = (const float*)d_in[6];
    const float* bias1  = (const float*)d_in[7];
    const float* bases2 = (const float*)d_in[8];
    const float* comp2  = (const float*)d_in[9];
    const float* root2  = (const float*)d_in[10];
    const float* bias2  = (const float*)d_in[11];
    const float* rel    = (const float*)d_in[12];
    const int* src = edge_index;
    const int* dst = edge_index + NE;

    char* ws = (char*)d_ws;
    size_t off_b = 0;
    auto alloc = [&](size_t bytes) { void* p = ws + off_b; off_b = (off_b + bytes + 255) & ~(size_t)255; return p; };

    unsigned short* x1   = (unsigned short*)alloc((size_t)N_NODES * 128 * 2);  // 25.6 MB
    unsigned short* x2   = (unsigned short*)alloc((size_t)N_NODES * 128 * 2);  // 25.6 MB
    unsigned short* wt1  = (unsigned short*)alloc(128 * 640 * 2);
    unsigned short* wt2  = (unsigned short*)alloc(128 * 640 * 2);
    unsigned short* relb = (unsigned short*)alloc(RR * DIM * 2);
    int*   deg    = (int*)alloc((size_t)N_NODES * 4);
    int*   cursor = (int*)alloc((size_t)N_NODES * 4);
    int*   offv   = (int*)alloc((size_t)(N_NODES + 1) * 4);
    int*   bsum   = (int*)alloc(NBLK * 4);
    int*   boff   = (int*)alloc(NBLK * 4);
    int4*  edesc  = (int4*)alloc((size_t)(NE + 64) * 16);                      // 6.4 MB + pad

    float* out = (float*)d_out;

    // k_pre first: x0/wt/rel/penalty + zero deg/cursor (replaces 2 memsets)
    k_pre<<<7403, 256, 0, stream>>>(ent, entb, bases1, root1, bases2, root2, rel,
                                    x1, wt1, wt2, relb, out, deg, cursor);
    k_deg<<<(NE + 255) / 256, 256, 0, stream>>>(dst, deg, NE);
    k_scan_block<<<NBLK, 256, 0, stream>>>(deg, bsum);
    k_scan_top<<<1, 256, 0, stream>>>(bsum, boff);
    k_scan_down<<<NBLK, 256, 0, stream>>>(deg, boff, offv);
    k_scatter<<<(NE + 255) / 256, 256, 0, stream>>>(src, dst, edge_type, offv, cursor, edesc, NE);
    k_norm2<<<(NE + 255) / 256, 256, 0, stream>>>(offv, edesc, NE);

    int fgrid = N_NODES / NPB;   // 3125 (exact)
    // layer 1: x1 -> x2 (relu)
    k_fused<<<fgrid, 512, 0, stream>>>(x1, edesc, offv, comp1, wt1, bias1, x2, 1);
    // layer 2: x2 -> x1 (no relu); x1 becomes xf
    k_fused<<<fgrid, 512, 0, stream>>>(x2, edesc, offv, comp2, wt2, bias2, x1, 0);
    // decode
    k_score<<<NE / 64, 256, 0, stream>>>(x1, src, dst, edge_type, relb, out, NE);
}

// Round 9
// 371.986 us; speedup vs baseline: 1.3091x; 1.0160x over previous
//
#include <hip/hip_runtime.h>

#define N_NODES 100000
#define DIM     128
#define RR      100
#define NE      400000
#define NBLK    196    // ceil(N_NODES / 512)
#define NPB     32     // dst nodes per fused block (100000 = 3125 * 32, exact)

typedef float  floatx4 __attribute__((ext_vector_type(4)));
typedef float  floatx2 __attribute__((ext_vector_type(2)));
typedef __bf16 bf16x8  __attribute__((ext_vector_type(8)));

static __device__ __forceinline__ unsigned short f2b(float f) {
    union { float f; unsigned int i; } v; v.f = f;
    unsigned int u = v.i;
    unsigned int r = (u + 0x7fffu + ((u >> 16) & 1u)) >> 16;   // RNE
    return (unsigned short)r;
}
static __device__ __forceinline__ float b2f(unsigned int u16) {
    union { unsigned int i; float f; } v; v.i = u16 << 16; return v.f;
}
static __device__ __forceinline__ unsigned packbf(float a, float b) {
    return (unsigned)f2b(a) | ((unsigned)f2b(b) << 16);
}

// ---- per-dst degree ------------------------------------------------------
__global__ void k_deg(const int* __restrict__ dst, int* __restrict__ deg, int E) {
    int e = blockIdx.x * 256 + threadIdx.x;
    if (e < E) atomicAdd(&deg[dst[e]], 1);
}

// ---- 2-level exclusive scan over deg[N] ----------------------------------
__global__ void k_scan_block(const int* __restrict__ deg, int* __restrict__ bsum) {
    __shared__ int sm[256];
    int b = blockIdx.x, t = threadIdx.x;
    int i0 = b * 512 + 2 * t;
    int a = (i0     < N_NODES) ? deg[i0]     : 0;
    int c = (i0 + 1 < N_NODES) ? deg[i0 + 1] : 0;
    sm[t] = a + c;
    __syncthreads();
    for (int s = 128; s > 0; s >>= 1) { if (t < s) sm[t] += sm[t + s]; __syncthreads(); }
    if (t == 0) bsum[b] = sm[0];
}

__global__ void k_scan_top(const int* __restrict__ bsum, int* __restrict__ boff) {
    __shared__ int sm[256];
    int t = threadIdx.x;
    int v = (t < NBLK) ? bsum[t] : 0;
    sm[t] = v;
    __syncthreads();
    for (int s = 1; s < 256; s <<= 1) {
        int u = (t >= s) ? sm[t - s] : 0;
        __syncthreads();
        sm[t] += u;
        __syncthreads();
    }
    if (t < NBLK) boff[t] = sm[t] - v;   // exclusive
}

__global__ void k_scan_down(const int* __restrict__ deg, const int* __restrict__ boff,
                            int* __restrict__ off) {
    __shared__ int sm[256];
    int b = blockIdx.x, t = threadIdx.x;
    int i0 = b * 512 + 2 * t;
    int a = (i0     < N_NODES) ? deg[i0]     : 0;
    int c = (i0 + 1 < N_NODES) ? deg[i0 + 1] : 0;
    int ts = a + c;
    sm[t] = ts;
    __syncthreads();
    for (int s = 1; s < 256; s <<= 1) {
        int u = (t >= s) ? sm[t - s] : 0;
        __syncthreads();
        sm[t] += u;
        __syncthreads();
    }
    int base = boff[b] + (sm[t] - ts);
    if (i0     < N_NODES) off[i0]     = base;
    if (i0 + 1 < N_NODES) off[i0 + 1] = base + a;
    if (b == 0 && t == 0) off[N_NODES] = NE;
}

// ---- scatter edges into dst-sorted CSR: desc = {src, et<<19|eidx, dst, norm}
__global__ void k_scatter(const int* __restrict__ src, const int* __restrict__ dst,
                          const int* __restrict__ et, const int* __restrict__ off,
                          int* __restrict__ cursor, int4* __restrict__ edesc, int E) {
    int e = blockIdx.x * 256 + threadIdx.x;
    if (e >= E) return;
    int d = dst[e];
    int pos = off[d] + atomicAdd(&cursor[d], 1);
    edesc[pos] = make_int4(src[e], (et[e] << 19) | e, d, 0);
}

// ---- schlichtkrull norm: one thread per CSR slot, O(deg) scan ------------
__global__ void k_norm2(const int* __restrict__ off, int4* __restrict__ edesc, int E) {
    int p = blockIdx.x * 256 + threadIdx.x;
    if (p >= E) return;
    int4 me = edesc[p];
    int myt = me.y >> 19;
    int p0 = off[me.z], p1 = off[me.z + 1];
    int c = 0;
    for (int j = p0; j < p1; ++j)
        c += ((((const int*)edesc)[4 * j + 1] >> 19) == myt) ? 1 : 0;
    ((int*)edesc)[4 * p + 3] = __float_as_int(1.0f / (float)c);
}

// ---- fused preprocessing: x0(vec8) | wt transpose | rel bf16 | zero | pen
// BLOCK RANGES (r7 crash lesson: rel branch MUST be exactly 12800/256 = 50
// blocks; 70 blocks wrote OOB past relb into deg -> corrupted CSR -> fault):
//   [0,6250)      x0: 12.8M elems, 8/thr
//   [6250,6570)   wt: 320 blocks = 81920 = 128*640
//   [6570,6620)   rel: 50 blocks = 12800
//   [6620,7402)   zero: 782 blocks = 200192 >= 200000
//   7402          penalty
__global__ void k_pre(const float* __restrict__ ent, const float* __restrict__ entb,
                      const float* __restrict__ bases1, const float* __restrict__ root1,
                      const float* __restrict__ bases2, const float* __restrict__ root2,
                      const float* __restrict__ rel,
                      unsigned short* __restrict__ x1,
                      unsigned short* __restrict__ wt1, unsigned short* __restrict__ wt2,
                      unsigned short* __restrict__ relb, float* __restrict__ out,
                      int* __restrict__ deg, int* __restrict__ cursor) {
    int b = blockIdx.x, t = threadIdx.x;
    if (b < 6250) {                                    // x0 = relu(ent + bias), 8/thr
        int i = (b * 256 + t) * 8;                     // 12.8M elems
        float4 v0 = *(const float4*)(ent + i);
        float4 v1 = *(const float4*)(ent + i + 4);
        int k = i & (DIM - 1);                         // 8-aligned col
        float4 e0 = *(const float4*)(entb + k);
        float4 e1 = *(const float4*)(entb + k + 4);
        unsigned r0 = packbf(fmaxf(v0.x + e0.x, 0.0f), fmaxf(v0.y + e0.y, 0.0f));
        unsigned r1 = packbf(fmaxf(v0.z + e0.z, 0.0f), fmaxf(v0.w + e0.w, 0.0f));
        unsigned r2 = packbf(fmaxf(v1.x + e1.x, 0.0f), fmaxf(v1.y + e1.y, 0.0f));
        unsigned r3 = packbf(fmaxf(v1.z + e1.z, 0.0f), fmaxf(v1.w + e1.w, 0.0f));
        *(uint4*)(x1 + i) = make_uint4(r0, r1, r2, r3);
    } else if (b < 6570) {                             // wt[m][k]: bases|root, row-major [128][640]
        int i = (b - 6250) * 256 + t;                  // 128*640
        int m = i / 640, k = i - m * 640;
        float v1, v2;
        if (k < 512) {
            int bb = k >> 7, kin = k & 127;
            v1 = bases1[(bb * 128 + kin) * 128 + m];
            v2 = bases2[(bb * 128 + kin) * 128 + m];
        } else {
            int kin = k - 512;
            v1 = root1[kin * 128 + m];
            v2 = root2[kin * 128 + m];
        }
        wt1[i] = f2b(v1);
        wt2[i] = f2b(v2);
    } else if (b < 6620) {                             // rel -> bf16 (EXACTLY 50 blocks)
        int i = (b - 6570) * 256 + t;                  // 12800
        relb[i] = f2b(rel[i]);
    } else if (b < 7402) {                             // zero deg + cursor
        int j = (b - 6620) * 256 + t;                  // 200192 slots
        if (j < N_NODES) deg[j] = 0;
        else if (j < 2 * N_NODES) cursor[j - N_NODES] = 0;
    } else {                                           // penalty
        __shared__ float sm[256];
        float v = 0.0f;
        for (int i = t; i < RR * DIM; i += 256) { float x = rel[i]; v += x * x; }
        sm[t] = v;
        __syncthreads();
        for (int s = 128; s > 0; s >>= 1) {
            if (t < s) sm[t] += sm[t + s];
            __syncthreads();
        }
        if (t == 0) out[NE] = sm[0];
    }
}

// ---- fused aggregate + GEMM ----------------------------------------------
// Block = 512 thr (8 waves), 32 dst nodes; wave owns 4 consecutive nodes.
// Phase A (r8 change): SOFTWARE-PIPELINED 16-edge batches. At batch i:
// issue 16 gathers for batch i+1 (from mdn, loaded during batch i-1), issue
// edesc load for batch i+2, THEN compute batch i from registers. Every
// gather gets a full batch of compute (~320cyc) to return (was: issued and
// consumed within the same batch -> ~600cyc L3 latency exposed per batch).
// edesc is allocated NE+64 entries so the +32 lookahead never faults.
// Phase B: MFMA K=640, dbuf Bs BK=64 (r4-proven best: issue-early loads,
// MFMA, write-late, one barrier/round).
// MEASURED LADDER (cross-round noise ~±7%, same code r4=94.5 / r8=107):
// r0 sync BK=128: 97 | r2 unstaged: 119 | r3 sync BK=64: 113 | r4 dbuf: 94.5
// | r6 dbuf BK=32: 101. Occupancy metric invariant — not a steering signal.
// LAUNCH BOUNDS: (512,4) = 128 VGPR cap. (512,8) spills (WRITE 25->310MB).
// Spill check: WRITE_SIZE must stay 25000 KB.
#define ACC(A) { A[0] += (floatx2){w0, w0} * xv; \
                 A[1] += (floatx2){w1, w1} * xv; \
                 A[2] += (floatx2){w2, w2} * xv; \
                 A[3] += (floatx2){w3, w3} * xv; }

__global__ __launch_bounds__(512, 4) void k_fused(const unsigned short* __restrict__ X,
                                                  const int4* __restrict__ edesc,
                                                  const int* __restrict__ off,
                                                  const float* __restrict__ comp,
                                                  const unsigned short* __restrict__ WT,
                                                  const float* __restrict__ bias,
                                                  unsigned short* __restrict__ out,
                                                  int do_relu) {
    __shared__ __align__(16) unsigned short Sacc[4 * NPB * 128];   // 32 KB, 4 planes
    __shared__ __align__(16) unsigned short Bs0[128 * 64];         // 16 KB, ping
    __shared__ __align__(16) unsigned short Bs1[128 * 64];         // 16 KB, pong
    __shared__ float4 Cs[RR];                                      // 1.6 KB

    const int t = threadIdx.x, wid = t >> 6, lane = t & 63;
    const int rbase = blockIdx.x * NPB;

    if (t < RR) Cs[t] = ((const float4*)comp)[t];
    __syncthreads();

    // ---------------- phase A: wave owns rows [nbase, nbase+4) ----------------
    {
        const int nbase = rbase + wid * 4;
        const int lo = off[nbase], hi = off[nbase + 4];
        const int l15 = lane & 15;
        floatx2 a0[4], a1[4], a2[4], a3[4];
#pragma unroll
        for (int c = 0; c < 4; ++c) {
            a0[c] = (floatx2)0.0f; a1[c] = (floatx2)0.0f;
            a2[c] = (floatx2)0.0f; a3[c] = (floatx2)0.0f;
        }
        if (lo < hi) {
            int4 mdc = edesc[lo + l15];                // batch 0 descriptors
            int4 mdn = edesc[lo + 16 + l15];           // batch 1 (pad-safe: NE+64)
            unsigned xpc[16], xpn[16];
            {
                int cnt0 = hi - lo; if (cnt0 > 16) cnt0 = 16;
#pragma unroll
                for (int u = 0; u < 16; ++u) {         // batch-0 gathers
                    int jc = (u < cnt0) ? u : 0;
                    int s = (int)__builtin_amdgcn_readlane((unsigned)mdc.x, (unsigned)jc);
                    xpc[u] = *(const unsigned*)(X + (size_t)s * 128 + 2 * lane);
                }
            }
            for (int base = lo; base < hi; base += 16) {
                int cnt = hi - base; if (cnt > 16) cnt = 16;
                int cntn = hi - (base + 16); if (cntn > 16) cntn = 16;
                if (cntn > 0) {                        // issue NEXT-batch gathers now
#pragma unroll
                    for (int u = 0; u < 16; ++u) {
                        int jc = (u < cntn) ? u : 0;
                        int s = (int)__builtin_amdgcn_readlane((unsigned)mdn.x, (unsigned)jc);
                        xpn[u] = *(const unsigned*)(X + (size_t)s * 128 + 2 * lane);
                    }
                }
                int4 mdt = edesc[base + 32 + l15];     // batch i+2 descriptors (pad-safe)
#pragma unroll
                for (int u = 0; u < 16; ++u) {         // compute CURRENT batch
                    if (u < cnt) {                     // wave-uniform guard
                        int row = (int)__builtin_amdgcn_readlane((unsigned)mdc.z, (unsigned)u) - nbase;
                        int tt  = (int)__builtin_amdgcn_readlane((unsigned)mdc.y, (unsigned)u) >> 19;
                        float w = __int_as_float(__builtin_amdgcn_readlane((unsigned)mdc.w, (unsigned)u));
                        float4 cc = Cs[tt];
                        floatx2 xv = {b2f(xpc[u] & 0xffffu), b2f(xpc[u] >> 16)};
                        float w0 = w * cc.x, w1 = w * cc.y, w2 = w * cc.z, w3 = w * cc.w;
                        if      (row == 0) ACC(a0)
                        else if (row == 1) ACC(a1)
                        else if (row == 2) ACC(a2)
                        else               ACC(a3)
                    }
                }
                mdc = mdn; mdn = mdt;                  // rotate pipeline
#pragma unroll
                for (int u = 0; u < 16; ++u) xpc[u] = xpn[u];
            }
        }
        // write 4 rows x 4 chunks, bf16-packed, xor-swizzled 16B chunks
        const int sw16 = lane >> 2, wo = 2 * (lane & 3);
#pragma unroll
        for (int r = 0; r < 4; ++r) {
            int R = wid * 4 + r;
            unsigned bo = (unsigned)(R * 128 + ((sw16 ^ (R & 15)) << 3) + wo);
            floatx2* A = (r == 0) ? a0 : (r == 1) ? a1 : (r == 2) ? a2 : a3;
#pragma unroll
            for (int c = 0; c < 4; ++c)
                *(unsigned*)(Sacc + c * (NPB * 128) + bo) = packbf(A[c].x, A[c].y);
        }
    }

    // ---------------- phase B: MFMA, m=32 n=128 K=640, dbuf Bs (BK=64) --------
    const int quad = lane >> 4, lr = lane & 15;
    const int wr = wid & 1, wc = wid >> 1;             // 2 m-tiles x 4 n-slices

    // this thread's two staging slots (1024 uint4 per 16KB chunk, 512 thr)
    const int srow0 = t >> 3,        sg0 = t & 7;          // idx = t
    const int srow1 = 64 + (t >> 3), sg1 = t & 7;          // idx = 512 + t
    const unsigned bo0 = (unsigned)(srow0 * 64 + ((sg0 ^ (srow0 & 7)) << 3));
    const unsigned bo1 = (unsigned)(srow1 * 64 + ((sg1 ^ (srow1 & 7)) << 3));

    // prologue: issue chunk-0 loads first (in flight across ax + barrier)
    uint4 p0 = *(const uint4*)(WT + (size_t)srow0 * 640 + sg0 * 8);
    uint4 p1 = *(const uint4*)(WT + (size_t)srow1 * 640 + sg1 * 8);

    // prefetch X fragments for chunks 8,9 (hidden behind chunk 0..7 compute)
    bf16x8 ax[4];
    {
        int grow = rbase + wr * 16 + lr;               // always < N (3125*32 exact)
#pragma unroll
        for (int ks = 0; ks < 4; ++ks)
            ax[ks] = *(const bf16x8*)(X + (size_t)grow * 128 + ks * 32 + quad * 8);
    }

    floatx4 acc[2];
    acc[0] = (floatx4)0.0f; acc[1] = (floatx4)0.0f;

    *(uint4*)(Bs0 + bo0) = p0;                         // compiler inserts vmcnt wait
    *(uint4*)(Bs0 + bo1) = p1;
    __syncthreads();                                   // Sacc + Bs0 ready

#pragma unroll
    for (int c = 0; c < 10; ++c) {
        const unsigned short* Bcur = (c & 1) ? Bs1 : Bs0;
        unsigned short*      Bnext = (c & 1) ? Bs0 : Bs1;
        uint4 n0, n1;
        if (c < 9) {                                   // issue next-chunk loads EARLY
            n0 = *(const uint4*)(WT + (size_t)srow0 * 640 + (c + 1) * 64 + sg0 * 8);
            n1 = *(const uint4*)(WT + (size_t)srow1 * 640 + (c + 1) * 64 + sg1 * 8);
        }
#pragma unroll
        for (int ks2 = 0; ks2 < 2; ++ks2) {
            int ks = (c & 1) * 2 + ks2;                // k-subgroup within 128-plane
            bf16x8 a, b0, b1;
            int R = wr * 16 + lr;
            if (c < 8) {
                int ch = ((ks * 4 + quad) ^ (R & 15)) << 3;
                a = *(const bf16x8*)(Sacc + (c >> 1) * (NPB * 128) + R * 128 + ch);
            } else {
                a = ax[(c - 8) * 2 + ks2];
            }
            int g = ks2 * 4 + quad;
            int sch = (g ^ (lr & 7)) << 3;
            b0 = *(const bf16x8*)(Bcur + (wc * 32 + lr) * 64 + sch);
            b1 = *(const bf16x8*)(Bcur + (wc * 32 + 16 + lr) * 64 + sch);
            acc[0] = __builtin_amdgcn_mfma_f32_16x16x32_bf16(a, b0, acc[0], 0, 0, 0);
            acc[1] = __builtin_amdgcn_mfma_f32_16x16x32_bf16(a, b1, acc[1], 0, 0, 0);
        }
        if (c < 9) {                                   // write-late: latency hidden
            *(uint4*)(Bnext + bo0) = n0;
            *(uint4*)(Bnext + bo1) = n1;
        }
        __syncthreads();                               // one barrier per round
    }

    // C/D layout: col=lane&15, row=quad*4+reg  [m89/m91-verified]
#pragma unroll
    for (int reg = 0; reg < 4; ++reg) {
        int R = wr * 16 + quad * 4 + reg;
        int grow = rbase + R;
#pragma unroll
        for (int nj = 0; nj < 2; ++nj) {
            int n = wc * 32 + nj * 16 + lr;
            float v = acc[nj][reg] + bias[n];
            if (do_relu) v = v > 0.0f ? v : 0.0f;
            out[(size_t)grow * 128 + n] = f2b(v);
        }
    }
}

// ---- DistMult score over CSR order (r8 change): one coalesced edesc int4
// replaces 3 scattered index loads; x[dst] gathers are near-sequential
// (deg~4 edges share a dst row -> L1/L2 hits); out[eidx] scatters 4B.
static __device__ __forceinline__ float dot8(uint4 a, uint4 r, uint4 b) {
    float v;
    v  = b2f(a.x & 0xffffu) * b2f(r.x & 0xffffu) * b2f(b.x & 0xffffu);
    v += b2f(a.x >> 16)     * b2f(r.x >> 16)     * b2f(b.x >> 16);
    v += b2f(a.y & 0xffffu) * b2f(r.y & 0xffffu) * b2f(b.y & 0xffffu);
    v += b2f(a.y >> 16)     * b2f(r.y >> 16)     * b2f(b.y >> 16);
    v += b2f(a.z & 0xffffu) * b2f(r.z & 0xffffu) * b2f(b.z & 0xffffu);
    v += b2f(a.z >> 16)     * b2f(r.z >> 16)     * b2f(b.z >> 16);
    v += b2f(a.w & 0xffffu) * b2f(r.w & 0xffffu) * b2f(b.w & 0xffffu);
    v += b2f(a.w >> 16)     * b2f(r.w >> 16)     * b2f(b.w >> 16);
    return v;
}

__global__ __launch_bounds__(256) void k_score(const unsigned short* __restrict__ xf,
                                               const int4* __restrict__ edesc,
                                               const unsigned short* __restrict__ relb,
                                               float* __restrict__ out, int E) {
    int g = threadIdx.x >> 4, li = threadIdx.x & 15;
    int p = blockIdx.x * 64 + g * 4;                   // grid 6250: 6250*64 = 400000 exact
    int4 m0 = edesc[p],     m1 = edesc[p + 1];
    int4 m2 = edesc[p + 2], m3 = edesc[p + 3];
    size_t lo = (size_t)li * 8;
    uint4 a0 = *(const uint4*)(xf + (size_t)m0.x * 128 + lo);
    uint4 b0 = *(const uint4*)(xf + (size_t)m0.z * 128 + lo);
    uint4 a1 = *(const uint4*)(xf + (size_t)m1.x * 128 + lo);
    uint4 b1 = *(const uint4*)(xf + (size_t)m1.z * 128 + lo);
    uint4 a2 = *(const uint4*)(xf + (size_t)m2.x * 128 + lo);
    uint4 b2 = *(const uint4*)(xf + (size_t)m2.z * 128 + lo);
    uint4 a3 = *(const uint4*)(xf + (size_t)m3.x * 128 + lo);
    uint4 b3 = *(const uint4*)(xf + (size_t)m3.z * 128 + lo);
    uint4 r0 = *(const uint4*)(relb + (size_t)(m0.y >> 19) * 128 + lo);
    uint4 r1 = *(const uint4*)(relb + (size_t)(m1.y >> 19) * 128 + lo);
    uint4 r2 = *(const uint4*)(relb + (size_t)(m2.y >> 19) * 128 + lo);
    uint4 r3 = *(const uint4*)(relb + (size_t)(m3.y >> 19) * 128 + lo);
    float v0 = dot8(a0, r0, b0);
    float v1 = dot8(a1, r1, b1);
    float v2 = dot8(a2, r2, b2);
    float v3 = dot8(a3, r3, b3);
#pragma unroll
    for (int s = 8; s > 0; s >>= 1) {
        v0 += __shfl_xor(v0, s, 16);
        v1 += __shfl_xor(v1, s, 16);
        v2 += __shfl_xor(v2, s, 16);
        v3 += __shfl_xor(v3, s, 16);
    }
    if (li == 0) {
        out[m0.y & 0x7ffff] = v0;
        out[m1.y & 0x7ffff] = v1;
        out[m2.y & 0x7ffff] = v2;
        out[m3.y & 0x7ffff] = v3;
    }
}

extern "C" void kernel_launch(void* const* d_in, const int* in_sizes, int n_in,
                              void* d_out, int out_size, void* d_ws, size_t ws_size,
                              hipStream_t stream) {
    (void)in_sizes; (void)n_in; (void)out_size; (void)ws_size;
    const int* edge_index = (const int*)d_in[0];
    const int* edge_type  = (const int*)d_in[1];
    const float* ent    = (const float*)d_in[2];
    const float* entb   = (const float*)d_in[3];
    const float* bases1 = (const float*)d_in[4];
    const float* comp1  = (const float*)d_in[5];
    const float* root1  = (const float*)d_in[6];
    const float* bias1  = (const float*)d_in[7];
    const float* bases2 = (const float*)d_in[8];
    const float* comp2  = (const float*)d_in[9];
    const float* root2  = (const float*)d_in[10];
    const float* bias2  = (const float*)d_in[11];
    const float* rel    = (const float*)d_in[12];
    const int* src = edge_index;
    const int* dst = edge_index + NE;

    char* ws = (char*)d_ws;
    size_t off_b = 0;
    auto alloc = [&](size_t bytes) { void* p = ws + off_b; off_b = (off_b + bytes + 255) & ~(size_t)255; return p; };

    unsigned short* x1   = (unsigned short*)alloc((size_t)N_NODES * 128 * 2);  // 25.6 MB
    unsigned short* x2   = (unsigned short*)alloc((size_t)N_NODES * 128 * 2);  // 25.6 MB
    unsigned short* wt1  = (unsigned short*)alloc(128 * 640 * 2);
    unsigned short* wt2  = (unsigned short*)alloc(128 * 640 * 2);
    unsigned short* relb = (unsigned short*)alloc(RR * DIM * 2);
    int*   deg    = (int*)alloc((size_t)N_NODES * 4);
    int*   cursor = (int*)alloc((size_t)N_NODES * 4);
    int*   offv   = (int*)alloc((size_t)(N_NODES + 1) * 4);
    int*   bsum   = (int*)alloc(NBLK * 4);
    int*   boff   = (int*)alloc(NBLK * 4);
    int4*  edesc  = (int4*)alloc((size_t)(NE + 64) * 16);                      // 6.4 MB + pad

    float* out = (float*)d_out;

    // k_pre first: x0/wt/rel/penalty + zero deg/cursor (replaces 2 memsets)
    k_pre<<<7403, 256, 0, stream>>>(ent, entb, bases1, root1, bases2, root2, rel,
                                    x1, wt1, wt2, relb, out, deg, cursor);
    k_deg<<<(NE + 255) / 256, 256, 0, stream>>>(dst, deg, NE);
    k_scan_block<<<NBLK, 256, 0, stream>>>(deg, bsum);
    k_scan_top<<<1, 256, 0, stream>>>(bsum, boff);
    k_scan_down<<<NBLK, 256, 0, stream>>>(deg, boff, offv);
    k_scatter<<<(NE + 255) / 256, 256, 0, stream>>>(src, dst, edge_type, offv, cursor, edesc, NE);
    k_norm2<<<(NE + 255) / 256, 256, 0, stream>>>(offv, edesc, NE);

    int fgrid = N_NODES / NPB;   // 3125 (exact)
    // layer 1: x1 -> x2 (relu)
    k_fused<<<fgrid, 512, 0, stream>>>(x1, edesc, offv, comp1, wt1, bias1, x2, 1);
    // layer 2: x2 -> x1 (no relu); x1 becomes xf
    k_fused<<<fgrid, 512, 0, stream>>>(x2, edesc, offv, comp2, wt2, bias2, x1, 0);
    // decode
    k_score<<<NE / 64, 256, 0, stream>>>(x1, edesc, relb, out, NE);
}

// Round 10
// 361.531 us; speedup vs baseline: 1.3469x; 1.0289x over previous
//
#include <hip/hip_runtime.h>

#define N_NODES 100000
#define DIM     128
#define RR      100
#define NE      400000
#define NBLK    196    // ceil(N_NODES / 512)
#define NPB     32     // dst nodes per fused block (100000 = 3125 * 32, exact)

typedef float  floatx4 __attribute__((ext_vector_type(4)));
typedef float  floatx2 __attribute__((ext_vector_type(2)));
typedef __bf16 bf16x8  __attribute__((ext_vector_type(8)));

static __device__ __forceinline__ unsigned short f2b(float f) {
    union { float f; unsigned int i; } v; v.f = f;
    unsigned int u = v.i;
    unsigned int r = (u + 0x7fffu + ((u >> 16) & 1u)) >> 16;   // RNE
    return (unsigned short)r;
}
static __device__ __forceinline__ float b2f(unsigned int u16) {
    union { unsigned int i; float f; } v; v.i = u16 << 16; return v.f;
}
static __device__ __forceinline__ unsigned packbf(float a, float b) {
    return (unsigned)f2b(a) | ((unsigned)f2b(b) << 16);
}
static __device__ __forceinline__ float rlf(float x, int u) {
    return __int_as_float(__builtin_amdgcn_readlane(__float_as_uint(x), (unsigned)u));
}

// ---- per-dst degree ------------------------------------------------------
__global__ void k_deg(const int* __restrict__ dst, int* __restrict__ deg, int E) {
    int e = blockIdx.x * 256 + threadIdx.x;
    if (e < E) atomicAdd(&deg[dst[e]], 1);
}

// ---- 2-level exclusive scan over deg[N] ----------------------------------
__global__ void k_scan_block(const int* __restrict__ deg, int* __restrict__ bsum) {
    __shared__ int sm[256];
    int b = blockIdx.x, t = threadIdx.x;
    int i0 = b * 512 + 2 * t;
    int a = (i0     < N_NODES) ? deg[i0]     : 0;
    int c = (i0 + 1 < N_NODES) ? deg[i0 + 1] : 0;
    sm[t] = a + c;
    __syncthreads();
    for (int s = 128; s > 0; s >>= 1) { if (t < s) sm[t] += sm[t + s]; __syncthreads(); }
    if (t == 0) bsum[b] = sm[0];
}

__global__ void k_scan_top(const int* __restrict__ bsum, int* __restrict__ boff) {
    __shared__ int sm[256];
    int t = threadIdx.x;
    int v = (t < NBLK) ? bsum[t] : 0;
    sm[t] = v;
    __syncthreads();
    for (int s = 1; s < 256; s <<= 1) {
        int u = (t >= s) ? sm[t - s] : 0;
        __syncthreads();
        sm[t] += u;
        __syncthreads();
    }
    if (t < NBLK) boff[t] = sm[t] - v;   // exclusive
}

__global__ void k_scan_down(const int* __restrict__ deg, const int* __restrict__ boff,
                            int* __restrict__ off) {
    __shared__ int sm[256];
    int b = blockIdx.x, t = threadIdx.x;
    int i0 = b * 512 + 2 * t;
    int a = (i0     < N_NODES) ? deg[i0]     : 0;
    int c = (i0 + 1 < N_NODES) ? deg[i0 + 1] : 0;
    int ts = a + c;
    sm[t] = ts;
    __syncthreads();
    for (int s = 1; s < 256; s <<= 1) {
        int u = (t >= s) ? sm[t - s] : 0;
        __syncthreads();
        sm[t] += u;
        __syncthreads();
    }
    int base = boff[b] + (sm[t] - ts);
    if (i0     < N_NODES) off[i0]     = base;
    if (i0 + 1 < N_NODES) off[i0 + 1] = base + a;
    if (b == 0 && t == 0) off[N_NODES] = NE;
}

// ---- scatter edges into dst-sorted CSR: desc = {src, et<<19|eidx, dst, 0}
__global__ void k_scatter(const int* __restrict__ src, const int* __restrict__ dst,
                          const int* __restrict__ et, const int* __restrict__ off,
                          int* __restrict__ cursor, int4* __restrict__ edesc, int E) {
    int e = blockIdx.x * 256 + threadIdx.x;
    if (e >= E) return;
    int d = dst[e];
    int pos = off[d] + atomicAdd(&cursor[d], 1);
    edesc[pos] = make_int4(src[e], (et[e] << 19) | e, d, 0);
}

// ---- schlichtkrull norm + per-edge fp32 weights for BOTH layers ----------
// ew_l[p] = (1/count) * comp_l[et] (float4). Removes the per-edge Cs LDS
// read (ds_read + lgkm wait on phase A's critical path) from k_fused.
__global__ void k_norm2(const int* __restrict__ off, const int4* __restrict__ edesc,
                        const float4* __restrict__ comp1, const float4* __restrict__ comp2,
                        float4* __restrict__ ew1, float4* __restrict__ ew2, int E) {
    int p = blockIdx.x * 256 + threadIdx.x;
    if (p >= E) return;
    int4 me = edesc[p];
    int myt = me.y >> 19;
    int p0 = off[me.z], p1 = off[me.z + 1];
    int c = 0;
    for (int j = p0; j < p1; ++j)
        c += ((((const int*)edesc)[4 * j + 1] >> 19) == myt) ? 1 : 0;
    float nrm = 1.0f / (float)c;
    float4 c1 = comp1[myt], c2 = comp2[myt];
    ew1[p] = make_float4(nrm * c1.x, nrm * c1.y, nrm * c1.z, nrm * c1.w);
    ew2[p] = make_float4(nrm * c2.x, nrm * c2.y, nrm * c2.z, nrm * c2.w);
}

// ---- fused preprocessing: x0(vec8) | wt transpose | rel bf16 | zero | pen
// BLOCK RANGES (r7 crash lesson: rel branch MUST be exactly 12800/256 = 50
// blocks; 70 blocks wrote OOB past relb into deg -> corrupted CSR -> fault):
//   [0,6250)      x0: 12.8M elems, 8/thr
//   [6250,6570)   wt: 320 blocks = 81920 = 128*640
//   [6570,6620)   rel: 50 blocks = 12800
//   [6620,7402)   zero: 782 blocks = 200192 >= 200000
//   7402          penalty
__global__ void k_pre(const float* __restrict__ ent, const float* __restrict__ entb,
                      const float* __restrict__ bases1, const float* __restrict__ root1,
                      const float* __restrict__ bases2, const float* __restrict__ root2,
                      const float* __restrict__ rel,
                      unsigned short* __restrict__ x1,
                      unsigned short* __restrict__ wt1, unsigned short* __restrict__ wt2,
                      unsigned short* __restrict__ relb, float* __restrict__ out,
                      int* __restrict__ deg, int* __restrict__ cursor) {
    int b = blockIdx.x, t = threadIdx.x;
    if (b < 6250) {                                    // x0 = relu(ent + bias), 8/thr
        int i = (b * 256 + t) * 8;                     // 12.8M elems
        float4 v0 = *(const float4*)(ent + i);
        float4 v1 = *(const float4*)(ent + i + 4);
        int k = i & (DIM - 1);                         // 8-aligned col
        float4 e0 = *(const float4*)(entb + k);
        float4 e1 = *(const float4*)(entb + k + 4);
        unsigned r0 = packbf(fmaxf(v0.x + e0.x, 0.0f), fmaxf(v0.y + e0.y, 0.0f));
        unsigned r1 = packbf(fmaxf(v0.z + e0.z, 0.0f), fmaxf(v0.w + e0.w, 0.0f));
        unsigned r2 = packbf(fmaxf(v1.x + e1.x, 0.0f), fmaxf(v1.y + e1.y, 0.0f));
        unsigned r3 = packbf(fmaxf(v1.z + e1.z, 0.0f), fmaxf(v1.w + e1.w, 0.0f));
        *(uint4*)(x1 + i) = make_uint4(r0, r1, r2, r3);
    } else if (b < 6570) {                             // wt[m][k]: bases|root, row-major [128][640]
        int i = (b - 6250) * 256 + t;                  // 128*640
        int m = i / 640, k = i - m * 640;
        float v1, v2;
        if (k < 512) {
            int bb = k >> 7, kin = k & 127;
            v1 = bases1[(bb * 128 + kin) * 128 + m];
            v2 = bases2[(bb * 128 + kin) * 128 + m];
        } else {
            int kin = k - 512;
            v1 = root1[kin * 128 + m];
            v2 = root2[kin * 128 + m];
        }
        wt1[i] = f2b(v1);
        wt2[i] = f2b(v2);
    } else if (b < 6620) {                             // rel -> bf16 (EXACTLY 50 blocks)
        int i = (b - 6570) * 256 + t;                  // 12800
        relb[i] = f2b(rel[i]);
    } else if (b < 7402) {                             // zero deg + cursor
        int j = (b - 6620) * 256 + t;                  // 200192 slots
        if (j < N_NODES) deg[j] = 0;
        else if (j < 2 * N_NODES) cursor[j - N_NODES] = 0;
    } else {                                           // penalty
        __shared__ float sm[256];
        float v = 0.0f;
        for (int i = t; i < RR * DIM; i += 256) { float x = rel[i]; v += x * x; }
        sm[t] = v;
        __syncthreads();
        for (int s = 128; s > 0; s >>= 1) {
            if (t < s) sm[t] += sm[t + s];
            __syncthreads();
        }
        if (t == 0) out[NE] = sm[0];
    }
}

// ---- fused aggregate + GEMM ----------------------------------------------
// Block = 512 thr (8 waves), 32 dst nodes; wave owns 4 consecutive nodes.
// Phase A: software-pipelined 16-edge batches (r9), per-edge weights now
// PRECOMPUTED fp32 (ew = norm*comp[et], r10): the per-edge Cs[tt] LDS read
// (ds_read_b128 + lgkm wait on the critical path) is replaced by 4
// readlanes from a coalesced ew register batch. Cs buffer + opening
// barrier removed entirely.
// Phase B: MFMA K=640, dbuf Bs BK=64 (r4-proven: issue-early, write-late,
// one barrier/round).
// MEASURED LADDER (cross-round noise ~±7%, same code r4=94.5 / r8=107):
// r0 sync BK=128: 97 | r2 unstaged: 119 | r3 sync BK=64: 113 | r4 dbuf: 94.5
// | r6 dbuf BK=32: 101 | r9 pipelined: 98. Occupancy metric not a signal.
// LAUNCH BOUNDS: (512,4) = 128 VGPR cap. (512,8) spills (WRITE 25->310MB).
// Spill check: WRITE_SIZE must stay 25000 KB.
#define ACC(A) { A[0] += (floatx2){w0, w0} * xv; \
                 A[1] += (floatx2){w1, w1} * xv; \
                 A[2] += (floatx2){w2, w2} * xv; \
                 A[3] += (floatx2){w3, w3} * xv; }

__global__ __launch_bounds__(512, 4) void k_fused(const unsigned short* __restrict__ X,
                                                  const int4* __restrict__ edesc,
                                                  const float4* __restrict__ ew,
                                                  const int* __restrict__ off,
                                                  const unsigned short* __restrict__ WT,
                                                  const float* __restrict__ bias,
                                                  unsigned short* __restrict__ out,
                                                  int do_relu) {
    __shared__ __align__(16) unsigned short Sacc[4 * NPB * 128];   // 32 KB, 4 planes
    __shared__ __align__(16) unsigned short Bs0[128 * 64];         // 16 KB, ping
    __shared__ __align__(16) unsigned short Bs1[128 * 64];         // 16 KB, pong

    const int t = threadIdx.x, wid = t >> 6, lane = t & 63;
    const int rbase = blockIdx.x * NPB;

    // ---------------- phase A: wave owns rows [nbase, nbase+4) ----------------
    {
        const int nbase = rbase + wid * 4;
        const int lo = off[nbase], hi = off[nbase + 4];
        const int l15 = lane & 15;
        floatx2 a0[4], a1[4], a2[4], a3[4];
#pragma unroll
        for (int c = 0; c < 4; ++c) {
            a0[c] = (floatx2)0.0f; a1[c] = (floatx2)0.0f;
            a2[c] = (floatx2)0.0f; a3[c] = (floatx2)0.0f;
        }
        if (lo < hi) {
            int4   mdc = edesc[lo + l15];              // batch 0 descriptors
            float4 mwc = ew[lo + l15];                 // batch 0 weights
            int4   mdn = edesc[lo + 16 + l15];         // batch 1 (pad-safe: NE+64)
            float4 mwn = ew[lo + 16 + l15];
            unsigned xpc[16], xpn[16];
            {
                int cnt0 = hi - lo; if (cnt0 > 16) cnt0 = 16;
#pragma unroll
                for (int u = 0; u < 16; ++u) {         // batch-0 gathers
                    int jc = (u < cnt0) ? u : 0;
                    int s = (int)__builtin_amdgcn_readlane((unsigned)mdc.x, (unsigned)jc);
                    xpc[u] = *(const unsigned*)(X + (size_t)s * 128 + 2 * lane);
                }
            }
            for (int base = lo; base < hi; base += 16) {
                int cnt = hi - base; if (cnt > 16) cnt = 16;
                int cntn = hi - (base + 16); if (cntn > 16) cntn = 16;
                if (cntn > 0) {                        // issue NEXT-batch gathers now
#pragma unroll
                    for (int u = 0; u < 16; ++u) {
                        int jc = (u < cntn) ? u : 0;
                        int s = (int)__builtin_amdgcn_readlane((unsigned)mdn.x, (unsigned)jc);
                        xpn[u] = *(const unsigned*)(X + (size_t)s * 128 + 2 * lane);
                    }
                }
                int4   mdt = edesc[base + 32 + l15];   // batch i+2 (pad-safe)
                float4 mwt = ew[base + 32 + l15];
#pragma unroll
                for (int u = 0; u < 16; ++u) {         // compute CURRENT batch
                    if (u < cnt) {                     // wave-uniform guard
                        int row = (int)__builtin_amdgcn_readlane((unsigned)mdc.z, (unsigned)u) - nbase;
                        float w0 = rlf(mwc.x, u), w1 = rlf(mwc.y, u);
                        float w2 = rlf(mwc.z, u), w3 = rlf(mwc.w, u);
                        floatx2 xv = {b2f(xpc[u] & 0xffffu), b2f(xpc[u] >> 16)};
                        if      (row == 0) ACC(a0)
                        else if (row == 1) ACC(a1)
                        else if (row == 2) ACC(a2)
                        else               ACC(a3)
                    }
                }
                mdc = mdn; mdn = mdt;                  // rotate pipeline
                mwc = mwn; mwn = mwt;
#pragma unroll
                for (int u = 0; u < 16; ++u) xpc[u] = xpn[u];
            }
        }
        // write 4 rows x 4 chunks, bf16-packed, xor-swizzled 16B chunks
        const int sw16 = lane >> 2, wo = 2 * (lane & 3);
#pragma unroll
        for (int r = 0; r < 4; ++r) {
            int R = wid * 4 + r;
            unsigned bo = (unsigned)(R * 128 + ((sw16 ^ (R & 15)) << 3) + wo);
            floatx2* A = (r == 0) ? a0 : (r == 1) ? a1 : (r == 2) ? a2 : a3;
#pragma unroll
            for (int c = 0; c < 4; ++c)
                *(unsigned*)(Sacc + c * (NPB * 128) + bo) = packbf(A[c].x, A[c].y);
        }
    }

    // ---------------- phase B: MFMA, m=32 n=128 K=640, dbuf Bs (BK=64) --------
    const int quad = lane >> 4, lr = lane & 15;
    const int wr = wid & 1, wc = wid >> 1;             // 2 m-tiles x 4 n-slices

    // this thread's two staging slots (1024 uint4 per 16KB chunk, 512 thr)
    const int srow0 = t >> 3,        sg0 = t & 7;          // idx = t
    const int srow1 = 64 + (t >> 3), sg1 = t & 7;          // idx = 512 + t
    const unsigned bo0 = (unsigned)(srow0 * 64 + ((sg0 ^ (srow0 & 7)) << 3));
    const unsigned bo1 = (unsigned)(srow1 * 64 + ((sg1 ^ (srow1 & 7)) << 3));

    // prologue: issue chunk-0 loads first (in flight across ax + barrier)
    uint4 p0 = *(const uint4*)(WT + (size_t)srow0 * 640 + sg0 * 8);
    uint4 p1 = *(const uint4*)(WT + (size_t)srow1 * 640 + sg1 * 8);

    // prefetch X fragments for chunks 8,9 (hidden behind chunk 0..7 compute)
    bf16x8 ax[4];
    {
        int grow = rbase + wr * 16 + lr;               // always < N (3125*32 exact)
#pragma unroll
        for (int ks = 0; ks < 4; ++ks)
            ax[ks] = *(const bf16x8*)(X + (size_t)grow * 128 + ks * 32 + quad * 8);
    }

    floatx4 acc[2];
    acc[0] = (floatx4)0.0f; acc[1] = (floatx4)0.0f;

    *(uint4*)(Bs0 + bo0) = p0;                         // compiler inserts vmcnt wait
    *(uint4*)(Bs0 + bo1) = p1;
    __syncthreads();                                   // Sacc + Bs0 ready

#pragma unroll
    for (int c = 0; c < 10; ++c) {
        const unsigned short* Bcur = (c & 1) ? Bs1 : Bs0;
        unsigned short*      Bnext = (c & 1) ? Bs0 : Bs1;
        uint4 n0, n1;
        if (c < 9) {                                   // issue next-chunk loads EARLY
            n0 = *(const uint4*)(WT + (size_t)srow0 * 640 + (c + 1) * 64 + sg0 * 8);
            n1 = *(const uint4*)(WT + (size_t)srow1 * 640 + (c + 1) * 64 + sg1 * 8);
        }
#pragma unroll
        for (int ks2 = 0; ks2 < 2; ++ks2) {
            int ks = (c & 1) * 2 + ks2;                // k-subgroup within 128-plane
            bf16x8 a, b0, b1;
            int R = wr * 16 + lr;
            if (c < 8) {
                int ch = ((ks * 4 + quad) ^ (R & 15)) << 3;
                a = *(const bf16x8*)(Sacc + (c >> 1) * (NPB * 128) + R * 128 + ch);
            } else {
                a = ax[(c - 8) * 2 + ks2];
            }
            int g = ks2 * 4 + quad;
            int sch = (g ^ (lr & 7)) << 3;
            b0 = *(const bf16x8*)(Bcur + (wc * 32 + lr) * 64 + sch);
            b1 = *(const bf16x8*)(Bcur + (wc * 32 + 16 + lr) * 64 + sch);
            acc[0] = __builtin_amdgcn_mfma_f32_16x16x32_bf16(a, b0, acc[0], 0, 0, 0);
            acc[1] = __builtin_amdgcn_mfma_f32_16x16x32_bf16(a, b1, acc[1], 0, 0, 0);
        }
        if (c < 9) {                                   // write-late: latency hidden
            *(uint4*)(Bnext + bo0) = n0;
            *(uint4*)(Bnext + bo1) = n1;
        }
        __syncthreads();                               // one barrier per round
    }

    // C/D layout: col=lane&15, row=quad*4+reg  [m89/m91-verified]
#pragma unroll
    for (int reg = 0; reg < 4; ++reg) {
        int R = wr * 16 + quad * 4 + reg;
        int grow = rbase + R;
#pragma unroll
        for (int nj = 0; nj < 2; ++nj) {
            int n = wc * 32 + nj * 16 + lr;
            float v = acc[nj][reg] + bias[n];
            if (do_relu) v = v > 0.0f ? v : 0.0f;
            out[(size_t)grow * 128 + n] = f2b(v);
        }
    }
}

// ---- DistMult score over CSR order (r8): one coalesced edesc int4
// replaces 3 scattered index loads; x[dst] gathers near-sequential.
static __device__ __forceinline__ float dot8(uint4 a, uint4 r, uint4 b) {
    float v;
    v  = b2f(a.x & 0xffffu) * b2f(r.x & 0xffffu) * b2f(b.x & 0xffffu);
    v += b2f(a.x >> 16)     * b2f(r.x >> 16)     * b2f(b.x >> 16);
    v += b2f(a.y & 0xffffu) * b2f(r.y & 0xffffu) * b2f(b.y & 0xffffu);
    v += b2f(a.y >> 16)     * b2f(r.y >> 16)     * b2f(b.y >> 16);
    v += b2f(a.z & 0xffffu) * b2f(r.z & 0xffffu) * b2f(b.z & 0xffffu);
    v += b2f(a.z >> 16)     * b2f(r.z >> 16)     * b2f(b.z >> 16);
    v += b2f(a.w & 0xffffu) * b2f(r.w & 0xffffu) * b2f(b.w & 0xffffu);
    v += b2f(a.w >> 16)     * b2f(r.w >> 16)     * b2f(b.w >> 16);
    return v;
}

__global__ __launch_bounds__(256) void k_score(const unsigned short* __restrict__ xf,
                                               const int4* __restrict__ edesc,
                                               const unsigned short* __restrict__ relb,
                                               float* __restrict__ out, int E) {
    int g = threadIdx.x >> 4, li = threadIdx.x & 15;
    int p = blockIdx.x * 64 + g * 4;                   // grid 6250: 6250*64 = 400000 exact
    int4 m0 = edesc[p],     m1 = edesc[p + 1];
    int4 m2 = edesc[p + 2], m3 = edesc[p + 3];
    size_t lo = (size_t)li * 8;
    uint4 a0 = *(const uint4*)(xf + (size_t)m0.x * 128 + lo);
    uint4 b0 = *(const uint4*)(xf + (size_t)m0.z * 128 + lo);
    uint4 a1 = *(const uint4*)(xf + (size_t)m1.x * 128 + lo);
    uint4 b1 = *(const uint4*)(xf + (size_t)m1.z * 128 + lo);
    uint4 a2 = *(const uint4*)(xf + (size_t)m2.x * 128 + lo);
    uint4 b2 = *(const uint4*)(xf + (size_t)m2.z * 128 + lo);
    uint4 a3 = *(const uint4*)(xf + (size_t)m3.x * 128 + lo);
    uint4 b3 = *(const uint4*)(xf + (size_t)m3.z * 128 + lo);
    uint4 r0 = *(const uint4*)(relb + (size_t)(m0.y >> 19) * 128 + lo);
    uint4 r1 = *(const uint4*)(relb + (size_t)(m1.y >> 19) * 128 + lo);
    uint4 r2 = *(const uint4*)(relb + (size_t)(m2.y >> 19) * 128 + lo);
    uint4 r3 = *(const uint4*)(relb + (size_t)(m3.y >> 19) * 128 + lo);
    float v0 = dot8(a0, r0, b0);
    float v1 = dot8(a1, r1, b1);
    float v2 = dot8(a2, r2, b2);
    float v3 = dot8(a3, r3, b3);
#pragma unroll
    for (int s = 8; s > 0; s >>= 1) {
        v0 += __shfl_xor(v0, s, 16);
        v1 += __shfl_xor(v1, s, 16);
        v2 += __shfl_xor(v2, s, 16);
        v3 += __shfl_xor(v3, s, 16);
    }
    if (li == 0) {
        out[m0.y & 0x7ffff] = v0;
        out[m1.y & 0x7ffff] = v1;
        out[m2.y & 0x7ffff] = v2;
        out[m3.y & 0x7ffff] = v3;
    }
}

extern "C" void kernel_launch(void* const* d_in, const int* in_sizes, int n_in,
                              void* d_out, int out_size, void* d_ws, size_t ws_size,
                              hipStream_t stream) {
    (void)in_sizes; (void)n_in; (void)out_size; (void)ws_size;
    const int* edge_index = (const int*)d_in[0];
    const int* edge_type  = (const int*)d_in[1];
    const float* ent    = (const float*)d_in[2];
    const float* entb   = (const float*)d_in[3];
    const float* bases1 = (const float*)d_in[4];
    const float* comp1  = (const float*)d_in[5];
    const float* root1  = (const float*)d_in[6];
    const float* bias1  = (const float*)d_in[7];
    const float* bases2 = (const float*)d_in[8];
    const float* comp2  = (const float*)d_in[9];
    const float* root2  = (const float*)d_in[10];
    const float* bias2  = (const float*)d_in[11];
    const float* rel    = (const float*)d_in[12];
    const int* src = edge_index;
    const int* dst = edge_index + NE;

    char* ws = (char*)d_ws;
    size_t off_b = 0;
    auto alloc = [&](size_t bytes) { void* p = ws + off_b; off_b = (off_b + bytes + 255) & ~(size_t)255; return p; };

    unsigned short* x1   = (unsigned short*)alloc((size_t)N_NODES * 128 * 2);  // 25.6 MB
    unsigned short* x2   = (unsigned short*)alloc((size_t)N_NODES * 128 * 2);  // 25.6 MB
    unsigned short* wt1  = (unsigned short*)alloc(128 * 640 * 2);
    unsigned short* wt2  = (unsigned short*)alloc(128 * 640 * 2);
    unsigned short* relb = (unsigned short*)alloc(RR * DIM * 2);
    int*   deg    = (int*)alloc((size_t)N_NODES * 4);
    int*   cursor = (int*)alloc((size_t)N_NODES * 4);
    int*   offv   = (int*)alloc((size_t)(N_NODES + 1) * 4);
    int*   bsum   = (int*)alloc(NBLK * 4);
    int*   boff   = (int*)alloc(NBLK * 4);
    int4*  edesc  = (int4*)alloc((size_t)(NE + 64) * 16);                      // 6.4 MB + pad
    float4* ew1   = (float4*)alloc((size_t)(NE + 64) * 16);                    // 6.4 MB + pad
    float4* ew2   = (float4*)alloc((size_t)(NE + 64) * 16);                    // 6.4 MB + pad

    float* out = (float*)d_out;

    // k_pre first: x0/wt/rel/penalty + zero deg/cursor (replaces 2 memsets)
    k_pre<<<7403, 256, 0, stream>>>(ent, entb, bases1, root1, bases2, root2, rel,
                                    x1, wt1, wt2, relb, out, deg, cursor);
    k_deg<<<(NE + 255) / 256, 256, 0, stream>>>(dst, deg, NE);
    k_scan_block<<<NBLK, 256, 0, stream>>>(deg, bsum);
    k_scan_top<<<1, 256, 0, stream>>>(bsum, boff);
    k_scan_down<<<NBLK, 256, 0, stream>>>(deg, boff, offv);
    k_scatter<<<(NE + 255) / 256, 256, 0, stream>>>(src, dst, edge_type, offv, cursor, edesc, NE);
    k_norm2<<<(NE + 255) / 256, 256, 0, stream>>>(offv, edesc,
                                                  (const float4*)comp1, (const float4*)comp2,
                                                  ew1, ew2, NE);

    int fgrid = N_NODES / NPB;   // 3125 (exact)
    // layer 1: x1 -> x2 (relu)
    k_fused<<<fgrid, 512, 0, stream>>>(x1, edesc, ew1, offv, wt1, bias1, x2, 1);
    // layer 2: x2 -> x1 (no relu); x1 becomes xf
    k_fused<<<fgrid, 512, 0, stream>>>(x2, edesc, ew2, offv, wt2, bias2, x1, 0);
    // decode
    k_score<<<NE / 64, 256, 0, stream>>>(x1, edesc, relb, out, NE);
}